// Round 11
// baseline (138.913 us; speedup 1.0000x reference)
//
#include <hip/hip_runtime.h>

#define NN 50000
#define NE 800000
#define NB 391            // dst buckets of 128 nodes (391*128 = 50048)
#define NBP 392           // padded row stride for pbh
#define CHUNK 8192        // edges per pass-1 block
#define NCH ((NE + CHUNK - 1) / CHUNK)  // 98 blocks

typedef __attribute__((ext_vector_type(8))) short bf16x8;
typedef __attribute__((ext_vector_type(4))) float f32x4;
typedef __attribute__((ext_vector_type(2))) float f32x2;

__device__ __forceinline__ unsigned pack_bf16x2(float a, float b) {
    unsigned ua = __float_as_uint(a);
    unsigned ub = __float_as_uint(b);
    ua = (ua + 0x7FFFu + ((ua >> 16) & 1u)) >> 16;
    ub = (ub + 0x7FFFu + ((ub >> 16) & 1u)) >> 16;
    return ua | (ub << 16);
}
// pack 4 floats -> 4 fp8 e4m3 (one u32)
__device__ __forceinline__ unsigned pack_fp8x4(float a, float b, float c, float d) {
    int w = __builtin_amdgcn_cvt_pk_fp8_f32(a, b, 0, false);
    w = __builtin_amdgcn_cvt_pk_fp8_f32(c, d, w, true);
    return (unsigned)w;
}

// ---------------- fused prep: bucket histogram (blocks 0..NCH-1) + W pack (blocks NCH..) ----------------
__global__ void k_hist(const int* __restrict__ dst, int* __restrict__ pbh,
                       const float* __restrict__ W1, const float* __restrict__ W2,
                       unsigned short* __restrict__ Wpk1, unsigned short* __restrict__ Wpk2) {
    const int t = threadIdx.x;
    if (blockIdx.x >= NCH) {  // W-pack part
        int gid = (blockIdx.x - NCH) * 256 + t;
        const float* W;
        unsigned short* Wpk;
        int idx, M;
        if (gid < 2048) { W = W1; Wpk = Wpk1; idx = gid; M = 128; }
        else if (gid < 3072) { W = W2; Wpk = Wpk2; idx = gid - 2048; M = 64; }
        else return;
        int l = idx & 63;
        int tt = (idx >> 6) & 3;
        int ct = idx >> 8;
        int col = ct * 16 + (l & 15);
        int k0 = tt * 32 + (l >> 4) * 8;
        unsigned* o = (unsigned*)(Wpk + (size_t)idx * 8);
#pragma unroll
        for (int j = 0; j < 8; j += 2)
            o[j >> 1] = pack_bf16x2(W[(size_t)(k0 + j) * M + col], W[(size_t)(k0 + j + 1) * M + col]);
        return;
    }
    __shared__ int h[NB];
    for (int j = t; j < NB; j += 256) h[j] = 0;
    __syncthreads();
    const int e0 = blockIdx.x * CHUNK;
#pragma unroll 8
    for (int i = 0; i < 32; ++i) {
        int e = e0 + t + i * 256;
        if (e < NE) atomicAdd(&h[dst[e] >> 7], 1);
    }
    __syncthreads();
    for (int j = t; j < NB; j += 256) pbh[blockIdx.x * NBP + j] = h[j];
}

// ---------------- bucket totals + exclusive scan + per-chunk bases ----------------
__global__ void k_bscan(int* __restrict__ pbh, int* __restrict__ bbase) {
    __shared__ int s[512];
    const int t = threadIdx.x;
    int tot = 0;
    if (t < NB) {
        int c = 0;
        for (; c + 4 <= NCH; c += 4)
            tot += pbh[c * NBP + t] + pbh[(c + 1) * NBP + t] +
                   pbh[(c + 2) * NBP + t] + pbh[(c + 3) * NBP + t];
        for (; c < NCH; ++c) tot += pbh[c * NBP + t];
    }
    s[t] = (t < NB) ? tot : 0;
    __syncthreads();
    for (int o = 1; o < 512; o <<= 1) {
        int a = (t >= o) ? s[t - o] : 0;
        __syncthreads();
        s[t] += a;
        __syncthreads();
    }
    int ex = s[t] - tot;
    if (t < NB) {
        bbase[t] = ex;
        int run = ex;
        for (int c = 0; c < NCH; ++c) {
            int tmp = pbh[c * NBP + t];
            pbh[c * NBP + t] = run;
            run += tmp;
        }
    }
    if (t == 0) bbase[NB] = NE;
}

// ---------------- pass 1: bucket-bin edges ----------------
__global__ void k_scat1(const int* __restrict__ src, const int* __restrict__ dst,
                        const int* __restrict__ pbh, unsigned* __restrict__ eord) {
    __shared__ int cur[NB];
    const int t = threadIdx.x;
    const int e0 = blockIdx.x * CHUNK;
    for (int j = t; j < NB; j += 256) cur[j] = pbh[blockIdx.x * NBP + j];
    __syncthreads();
#pragma unroll 8
    for (int i = 0; i < 32; ++i) {
        int e = e0 + t + i * 256;
        if (e < NE) {
            unsigned s = (unsigned)src[e];
            unsigned d = (unsigned)dst[e];
            int pos = atomicAdd(&cur[d >> 7], 1);
            eord[pos] = ((d & 127u) << 16) | s;
        }
    }
}

// ---------------- pass 2: within-bucket sort + row_start + dinv ----------------
__global__ void k_scat2(const int* __restrict__ bbase, const unsigned* __restrict__ eord,
                        unsigned short* __restrict__ esrc16, int* __restrict__ row_start,
                        float* __restrict__ dinv) {
    __shared__ int cnt[128];
    __shared__ int pre[128];
    __shared__ int cur[128];
    const int b = blockIdx.x, t = threadIdx.x, d0 = b << 7;
    if (t < 128) cnt[t] = 0;
    __syncthreads();
    const int beg = bbase[b], end = bbase[b + 1];
    for (int i = beg + t; i < end; i += 256) atomicAdd(&cnt[(eord[i] >> 16) & 127], 1);
    __syncthreads();
    int v = (t < 128) ? cnt[t] : 0;
    if (t < 128) pre[t] = v;
    __syncthreads();
    for (int o = 1; o < 128; o <<= 1) {
        int a = (t < 128 && t >= o) ? pre[t - o] : 0;
        __syncthreads();
        if (t < 128) pre[t] += a;
        __syncthreads();
    }
    if (t < 128) {
        int ex = beg + pre[t] - v;
        int d = d0 + t;
        if (d < NN) {
            row_start[d] = ex;
            dinv[d] = rsqrtf((float)(v + 1));  // +1 self-loop
        }
        cur[t] = ex;
    }
    if (b == NB - 1 && t == 0) row_start[NN] = NE;
    __syncthreads();
    for (int i = beg + t; i < end; i += 256) {
        unsigned x = eord[i];
        int pos = atomicAdd(&cur[(x >> 16) & 127], 1);
        esrc16[pos] = (unsigned short)(x & 0xFFFFu);
    }
}

// ---------------- MFMA GEMM1: two 3.2MB fp8 half-tables (cols 0-63 / 64-127) ----------------
// 4 waves/block, wave = 16 rows. lane l: row r0+(l&15), cols c*16 + lq*4 + q.
__global__ __launch_bounds__(256) void k_gemm1(const float* __restrict__ X,
                                               const unsigned short* __restrict__ Wpk,
                                               const float* __restrict__ dinv,
                                               unsigned* __restrict__ H1a,
                                               unsigned* __restrict__ H1b) {
    const int t = threadIdx.x;
    const int w = t >> 6, l = t & 63;
    const int row = blockIdx.x * 64 + w * 16 + (l & 15);
    const int rc = row < NN ? row : NN - 1;
    const int lq = l >> 4;
    f32x4 acc[8];
#pragma unroll
    for (int c = 0; c < 8; ++c) acc[c] = (f32x4){0.f, 0.f, 0.f, 0.f};
#pragma unroll
    for (int tt = 0; tt < 4; ++tt) {
        const float4* xp = (const float4*)(X + (size_t)rc * 128 + tt * 32 + lq * 8);
        float4 xa = xp[0], xb = xp[1];
        bf16x8 xf;
        unsigned* xu = (unsigned*)&xf;
        xu[0] = pack_bf16x2(xa.x, xa.y);
        xu[1] = pack_bf16x2(xa.z, xa.w);
        xu[2] = pack_bf16x2(xb.x, xb.y);
        xu[3] = pack_bf16x2(xb.z, xb.w);
#pragma unroll
        for (int c = 0; c < 8; ++c) {
            bf16x8 wf = *(const bf16x8*)(Wpk + (size_t)((c * 4 + tt) * 64 + l) * 8);
            acc[c] = __builtin_amdgcn_mfma_f32_16x16x32_bf16(wf, xf, acc[c], 0, 0, 0);
        }
    }
    if (row < NN) {
        float s = dinv[row];
        unsigned* ra = H1a + (size_t)row * 16;
        unsigned* rb = H1b + (size_t)row * 16;
#pragma unroll
        for (int c = 0; c < 8; ++c) {
            unsigned pv = pack_fp8x4(acc[c][0] * s, acc[c][1] * s, acc[c][2] * s, acc[c][3] * s);
            if (c < 4) ra[c * 4 + lq] = pv;
            else rb[(c - 4) * 4 + lq] = pv;
        }
    }
}

// ---------------- MFMA GEMM2: H2f8[N,16 u32] = fp8(dinv * (X2 @ W2)) ----------------
__global__ __launch_bounds__(256) void k_gemm2(const unsigned short* __restrict__ Xb,
                                               const unsigned short* __restrict__ Wpk,
                                               const float* __restrict__ dinv,
                                               unsigned* __restrict__ H2) {
    const int t = threadIdx.x;
    const int w = t >> 6, l = t & 63;
    const int row = blockIdx.x * 64 + w * 16 + (l & 15);
    const int rc = row < NN ? row : NN - 1;
    const int lq = l >> 4;
    f32x4 acc[4];
#pragma unroll
    for (int c = 0; c < 4; ++c) acc[c] = (f32x4){0.f, 0.f, 0.f, 0.f};
#pragma unroll
    for (int tt = 0; tt < 4; ++tt) {
        bf16x8 xf = *(const bf16x8*)(Xb + (size_t)rc * 128 + tt * 32 + lq * 8);
#pragma unroll
        for (int c = 0; c < 4; ++c) {
            bf16x8 wf = *(const bf16x8*)(Wpk + (size_t)((c * 4 + tt) * 64 + l) * 8);
            acc[c] = __builtin_amdgcn_mfma_f32_16x16x32_bf16(wf, xf, acc[c], 0, 0, 0);
        }
    }
    if (row < NN) {
        float s = dinv[row];
        unsigned* orow = H2 + (size_t)row * 16;
#pragma unroll
        for (int c = 0; c < 4; ++c)
            orow[c * 4 + lq] = pack_fp8x4(acc[c][0] * s, acc[c][1] * s, acc[c][2] * s, acc[c][3] * s);
    }
}

// ---------------- layer-1 aggregate: column-split halves, parity-interleaved blocks ----------------
// half = blockIdx&1 (round-robin XCD assignment keeps each XCD on one 3.2MB table).
// quarter-wave per node; lane = u32 (4 fp8 cols) of the half's 64B row.
__global__ void k_agg1(const int* __restrict__ row_start, const unsigned short* __restrict__ esrc,
                       const unsigned* __restrict__ H1a, const unsigned* __restrict__ H1b,
                       const float* __restrict__ dinv, const float* __restrict__ b,
                       unsigned* __restrict__ X2b) {
    const int half = blockIdx.x & 1;
    int wid = (blockIdx.x >> 1) * 4 + (threadIdx.x >> 6);
    int lane = threadIdx.x & 63;
    if (wid >= NN) return;
    const unsigned* H = half ? H1b : H1a;
    int beg = row_start[wid];
    int n = row_start[wid + 1] - beg;
    int q = lane >> 4, l16 = lane & 15;
    int qb = beg + ((n * q) >> 2);
    int qe = beg + ((n * (q + 1)) >> 2);
    float a0 = 0.f, a1 = 0.f, a2 = 0.f, a3 = 0.f;
    int j = qb;
    for (; j + 4 <= qe; j += 4) {
        int s0 = esrc[j], s1 = esrc[j + 1], s2 = esrc[j + 2], s3 = esrc[j + 3];
        unsigned v0 = H[(size_t)s0 * 16 + l16];
        unsigned v1 = H[(size_t)s1 * 16 + l16];
        unsigned v2 = H[(size_t)s2 * 16 + l16];
        unsigned v3 = H[(size_t)s3 * 16 + l16];
#pragma unroll
        for (int k = 0; k < 4; ++k) {
            unsigned v = (k == 0) ? v0 : (k == 1) ? v1 : (k == 2) ? v2 : v3;
            f32x2 p0 = __builtin_amdgcn_cvt_pk_f32_fp8(v, false);
            f32x2 p1 = __builtin_amdgcn_cvt_pk_f32_fp8(v, true);
            a0 += p0.x; a1 += p0.y; a2 += p1.x; a3 += p1.y;
        }
    }
    for (; j < qe; ++j) {
        unsigned v = H[(size_t)esrc[j] * 16 + l16];
        f32x2 p0 = __builtin_amdgcn_cvt_pk_f32_fp8(v, false);
        f32x2 p1 = __builtin_amdgcn_cvt_pk_f32_fp8(v, true);
        a0 += p0.x; a1 += p0.y; a2 += p1.x; a3 += p1.y;
    }
    if (q == 0) {  // self-loop, counted once
        unsigned v = H[(size_t)wid * 16 + l16];
        f32x2 p0 = __builtin_amdgcn_cvt_pk_f32_fp8(v, false);
        f32x2 p1 = __builtin_amdgcn_cvt_pk_f32_fp8(v, true);
        a0 += p0.x; a1 += p0.y; a2 += p1.x; a3 += p1.y;
    }
    a0 += __shfl_xor(a0, 16); a0 += __shfl_xor(a0, 32);
    a1 += __shfl_xor(a1, 16); a1 += __shfl_xor(a1, 32);
    a2 += __shfl_xor(a2, 16); a2 += __shfl_xor(a2, 32);
    a3 += __shfl_xor(a3, 16); a3 += __shfl_xor(a3, 32);
    if (q == 0) {
        float di = dinv[wid];
        float4 bv = ((const float4*)b)[half * 16 + l16];
        uint2 st;
        st.x = pack_bf16x2(fmaxf(fmaf(di, a0, bv.x), 0.f), fmaxf(fmaf(di, a1, bv.y), 0.f));
        st.y = pack_bf16x2(fmaxf(fmaf(di, a2, bv.z), 0.f), fmaxf(fmaf(di, a3, bv.w), 0.f));
        ((uint2*)X2b)[(size_t)wid * 32 + half * 16 + l16] = st;
    }
}

// ---------------- layer-2 aggregate + log_softmax: quarter-wave, u32/lane = 64B fp8 row/load ----------------
__global__ void k_agg2_lsm(const int* __restrict__ row_start, const unsigned short* __restrict__ esrc,
                           const unsigned* __restrict__ H2, const float* __restrict__ dinv,
                           const float* __restrict__ b, float* __restrict__ OUT) {
    int wid = (blockIdx.x * blockDim.x + threadIdx.x) >> 6;
    int lane = threadIdx.x & 63;
    if (wid >= NN) return;
    int beg = row_start[wid];
    int n = row_start[wid + 1] - beg;
    int q = lane >> 4, l16 = lane & 15;
    int qb = beg + ((n * q) >> 2);
    int qe = beg + ((n * (q + 1)) >> 2);
    float a0 = 0.f, a1 = 0.f, a2 = 0.f, a3 = 0.f;
    int j = qb;
    for (; j + 4 <= qe; j += 4) {
        int s0 = esrc[j], s1 = esrc[j + 1], s2 = esrc[j + 2], s3 = esrc[j + 3];
        unsigned v0 = H2[(size_t)s0 * 16 + l16];
        unsigned v1 = H2[(size_t)s1 * 16 + l16];
        unsigned v2 = H2[(size_t)s2 * 16 + l16];
        unsigned v3 = H2[(size_t)s3 * 16 + l16];
#pragma unroll
        for (int k = 0; k < 4; ++k) {
            unsigned v = (k == 0) ? v0 : (k == 1) ? v1 : (k == 2) ? v2 : v3;
            f32x2 p0 = __builtin_amdgcn_cvt_pk_f32_fp8(v, false);
            f32x2 p1 = __builtin_amdgcn_cvt_pk_f32_fp8(v, true);
            a0 += p0.x; a1 += p0.y; a2 += p1.x; a3 += p1.y;
        }
    }
    for (; j < qe; ++j) {
        unsigned v = H2[(size_t)esrc[j] * 16 + l16];
        f32x2 p0 = __builtin_amdgcn_cvt_pk_f32_fp8(v, false);
        f32x2 p1 = __builtin_amdgcn_cvt_pk_f32_fp8(v, true);
        a0 += p0.x; a1 += p0.y; a2 += p1.x; a3 += p1.y;
    }
    if (q == 0) {  // self-loop
        unsigned v = H2[(size_t)wid * 16 + l16];
        f32x2 p0 = __builtin_amdgcn_cvt_pk_f32_fp8(v, false);
        f32x2 p1 = __builtin_amdgcn_cvt_pk_f32_fp8(v, true);
        a0 += p0.x; a1 += p0.y; a2 += p1.x; a3 += p1.y;
    }
    a0 += __shfl_xor(a0, 16); a0 += __shfl_xor(a0, 32);
    a1 += __shfl_xor(a1, 16); a1 += __shfl_xor(a1, 32);
    a2 += __shfl_xor(a2, 16); a2 += __shfl_xor(a2, 32);
    a3 += __shfl_xor(a3, 16); a3 += __shfl_xor(a3, 32);
    float di = dinv[wid];
    float4 bv = ((const float4*)b)[l16];
    float v0 = fmaf(di, a0, bv.x);
    float v1 = fmaf(di, a1, bv.y);
    float v2 = fmaf(di, a2, bv.z);
    float v3 = fmaf(di, a3, bv.w);
    float m = fmaxf(fmaxf(v0, v1), fmaxf(v2, v3));
#pragma unroll
    for (int o = 8; o > 0; o >>= 1) m = fmaxf(m, __shfl_xor(m, o));
    float s = expf(v0 - m) + expf(v1 - m) + expf(v2 - m) + expf(v3 - m);
#pragma unroll
    for (int o = 8; o > 0; o >>= 1) s += __shfl_xor(s, o);
    float ls = m + logf(s);
    if (q == 0) {
        float4 o4;
        o4.x = v0 - ls;
        o4.y = v1 - ls;
        o4.z = v2 - ls;
        o4.w = v3 - ls;
        ((float4*)OUT)[(size_t)wid * 16 + l16] = o4;
    }
}

extern "C" void kernel_launch(void* const* d_in, const int* in_sizes, int n_in,
                              void* d_out, int out_size, void* d_ws, size_t ws_size,
                              hipStream_t stream) {
    const float* x = (const float*)d_in[0];
    const int* ei = (const int*)d_in[1];  // [2, NE] int32
    const float* W1 = (const float*)d_in[2];
    const float* b1 = (const float*)d_in[3];
    const float* W2 = (const float*)d_in[4];
    const float* b2 = (const float*)d_in[5];
    float* out = (float*)d_out;

    const int* src = ei;
    const int* dst = ei + NE;

    // workspace layout (all segments 16B-aligned)
    int* bbase = (int*)d_ws;                                 // 400
    int* pbh = bbase + 400;                                  // NCH*NBP
    unsigned* eord = (unsigned*)(pbh + NCH * NBP);           // NE
    unsigned short* esrc16 = (unsigned short*)(eord + NE);   // NE
    int* row_start = (int*)(esrc16 + NE);                    // 50016
    float* dinv = (float*)(row_start + 50016);               // NN
    unsigned short* Wpk1 = (unsigned short*)(dinv + NN);     // 2048*8 bf16 (32KB)
    unsigned short* Wpk2 = Wpk1 + 2048 * 8;                  // 1024*8 bf16 (16KB)
    unsigned* H1a = (unsigned*)(Wpk2 + 1024 * 8);            // NN*16 u32 (fp8 cols 0-63, 3.2MB)
    unsigned* H1b = H1a + (size_t)NN * 16;                   // NN*16 u32 (fp8 cols 64-127, 3.2MB)
    unsigned* H2f8 = H1b + (size_t)NN * 16;                  // NN*16 u32 (fp8x4, 3.2MB)
    unsigned* X2b = H2f8 + (size_t)NN * 16;                  // NN*64 u32 (bf16 row-major)

    k_hist<<<NCH + 12, 256, 0, stream>>>(dst, pbh, W1, W2, Wpk1, Wpk2);
    k_bscan<<<1, 512, 0, stream>>>(pbh, bbase);
    k_scat1<<<NCH, 256, 0, stream>>>(src, dst, pbh, eord);
    k_scat2<<<NB, 256, 0, stream>>>(bbase, eord, esrc16, row_start, dinv);

    // layer 1
    k_gemm1<<<(NN + 63) / 64, 256, 0, stream>>>(x, Wpk1, dinv, H1a, H1b);
    k_agg1<<<((NN + 3) / 4) * 2, 256, 0, stream>>>(row_start, esrc16, H1a, H1b, dinv, b1, X2b);
    // layer 2
    k_gemm2<<<(NN + 63) / 64, 256, 0, stream>>>((const unsigned short*)X2b, Wpk2, dinv, H2f8);
    k_agg2_lsm<<<(NN * 64 + 255) / 256, 256, 0, stream>>>(row_start, esrc16, H2f8, dinv, b2, out);
}

// Round 12
// 124.610 us; speedup vs baseline: 1.1148x; 1.1148x over previous
//
#include <hip/hip_runtime.h>

#define NN 50000
#define NE 800000
#define NB 391            // dst buckets of 128 nodes (391*128 = 50048)
#define NBP 392           // padded row stride for pbh
#define CHUNK 8192        // edges per pass-1 block
#define NCH ((NE + CHUNK - 1) / CHUNK)  // 98 blocks

typedef __attribute__((ext_vector_type(8))) short bf16x8;
typedef __attribute__((ext_vector_type(4))) float f32x4;
typedef __attribute__((ext_vector_type(2))) float f32x2;

__device__ __forceinline__ unsigned pack_bf16x2(float a, float b) {
    unsigned ua = __float_as_uint(a);
    unsigned ub = __float_as_uint(b);
    ua = (ua + 0x7FFFu + ((ua >> 16) & 1u)) >> 16;
    ub = (ub + 0x7FFFu + ((ub >> 16) & 1u)) >> 16;
    return ua | (ub << 16);
}
// pack 4 floats -> 4 fp8 e4m3 (one u32)
__device__ __forceinline__ unsigned pack_fp8x4(float a, float b, float c, float d) {
    int w = __builtin_amdgcn_cvt_pk_fp8_f32(a, b, 0, false);
    w = __builtin_amdgcn_cvt_pk_fp8_f32(c, d, w, true);
    return (unsigned)w;
}

// ---------------- fused prep: per-chunk bucket histogram + W pack ----------------
__global__ void k_hist(const int* __restrict__ dst, int* __restrict__ pbh,
                       const float* __restrict__ W1, const float* __restrict__ W2,
                       unsigned short* __restrict__ Wpk1, unsigned short* __restrict__ Wpk2) {
    const int t = threadIdx.x;
    if (blockIdx.x >= NCH) {  // W-pack part
        int gid = (blockIdx.x - NCH) * 256 + t;
        const float* W;
        unsigned short* Wpk;
        int idx, M;
        if (gid < 2048) { W = W1; Wpk = Wpk1; idx = gid; M = 128; }
        else if (gid < 3072) { W = W2; Wpk = Wpk2; idx = gid - 2048; M = 64; }
        else return;
        int l = idx & 63;
        int tt = (idx >> 6) & 3;
        int ct = idx >> 8;
        int col = ct * 16 + (l & 15);
        int k0 = tt * 32 + (l >> 4) * 8;
        unsigned* o = (unsigned*)(Wpk + (size_t)idx * 8);
#pragma unroll
        for (int j = 0; j < 8; j += 2)
            o[j >> 1] = pack_bf16x2(W[(size_t)(k0 + j) * M + col], W[(size_t)(k0 + j + 1) * M + col]);
        return;
    }
    __shared__ int h[NB];
    for (int j = t; j < NB; j += 256) h[j] = 0;
    __syncthreads();
    const int e0 = blockIdx.x * CHUNK;
#pragma unroll 8
    for (int i = 0; i < 32; ++i) {
        int e = e0 + t + i * 256;
        if (e < NE) atomicAdd(&h[dst[e] >> 7], 1);
    }
    __syncthreads();
    for (int j = t; j < NB; j += 256) pbh[blockIdx.x * NBP + j] = h[j];
}

// ---------------- bucket totals + exclusive scan -> bbase, bcur (no per-chunk rewrite) ----------------
__global__ void k_bscan(const int* __restrict__ pbh, int* __restrict__ bbase,
                        int* __restrict__ bcur) {
    __shared__ int s[512];
    const int t = threadIdx.x;
    int tot = 0;
    if (t < NB) {
        int c = 0;
        for (; c + 4 <= NCH; c += 4)
            tot += pbh[c * NBP + t] + pbh[(c + 1) * NBP + t] +
                   pbh[(c + 2) * NBP + t] + pbh[(c + 3) * NBP + t];
        for (; c < NCH; ++c) tot += pbh[c * NBP + t];
    }
    s[t] = (t < NB) ? tot : 0;
    __syncthreads();
    for (int o = 1; o < 512; o <<= 1) {
        int a = (t >= o) ? s[t - o] : 0;
        __syncthreads();
        s[t] += a;
        __syncthreads();
    }
    int ex = s[t] - tot;
    if (t < NB) {
        bbase[t] = ex;
        bcur[t] = ex;
    }
    if (t == 0) bbase[NB] = NE;
}

// ---------------- pass 1: bucket-bin edges (block reserves ranges via bcur atomics) ----------------
// packed edge: [31:16]=dst, [15:0]=src ; bucket = pk>>23
__global__ void k_scat1(const int* __restrict__ src, const int* __restrict__ dst,
                        int* __restrict__ bcur, unsigned* __restrict__ eord) {
    __shared__ int hist[NB];
    __shared__ int gbase[NB];
    const int t = threadIdx.x;
    const int e0 = blockIdx.x * CHUNK;
    for (int j = t; j < NB; j += 256) hist[j] = 0;
    __syncthreads();
    unsigned pk[32];
#pragma unroll
    for (int i = 0; i < 32; ++i) {
        int e = e0 + t + i * 256;
        pk[i] = 0xFFFFFFFFu;
        if (e < NE) {
            unsigned s = (unsigned)src[e];
            unsigned d = (unsigned)dst[e];
            pk[i] = (d << 16) | s;
            atomicAdd(&hist[d >> 7], 1);
        }
    }
    __syncthreads();
    for (int j = t; j < NB; j += 256) {
        int c = hist[j];
        gbase[j] = c ? atomicAdd(&bcur[j], c) : 0;
        hist[j] = 0;  // reuse as within-block cursor
    }
    __syncthreads();
#pragma unroll
    for (int i = 0; i < 32; ++i) {
        if (pk[i] != 0xFFFFFFFFu) {
            int bk = pk[i] >> 23;
            int pos = gbase[bk] + atomicAdd(&hist[bk], 1);
            eord[pos] = pk[i];
        }
    }
}

// ---------------- pass 2: within-bucket sort + row_start + dinv ----------------
__global__ void k_scat2(const int* __restrict__ bbase, const unsigned* __restrict__ eord,
                        unsigned short* __restrict__ esrc16, int* __restrict__ row_start,
                        float* __restrict__ dinv) {
    __shared__ int cnt[128];
    __shared__ int pre[128];
    __shared__ int cur[128];
    const int b = blockIdx.x, t = threadIdx.x, d0 = b << 7;
    if (t < 128) cnt[t] = 0;
    __syncthreads();
    const int beg = bbase[b], end = bbase[b + 1];
    for (int i = beg + t; i < end; i += 256) atomicAdd(&cnt[(eord[i] >> 16) & 127], 1);
    __syncthreads();
    int v = (t < 128) ? cnt[t] : 0;
    if (t < 128) pre[t] = v;
    __syncthreads();
    for (int o = 1; o < 128; o <<= 1) {
        int a = (t < 128 && t >= o) ? pre[t - o] : 0;
        __syncthreads();
        if (t < 128) pre[t] += a;
        __syncthreads();
    }
    if (t < 128) {
        int ex = beg + pre[t] - v;
        int d = d0 + t;
        if (d < NN) {
            row_start[d] = ex;
            dinv[d] = rsqrtf((float)(v + 1));  // +1 self-loop
        }
        cur[t] = ex;
    }
    if (b == NB - 1 && t == 0) row_start[NN] = NE;
    __syncthreads();
    for (int i = beg + t; i < end; i += 256) {
        unsigned x = eord[i];
        int pos = atomicAdd(&cur[(x >> 16) & 127], 1);
        esrc16[pos] = (unsigned short)(x & 0xFFFFu);
    }
}

// ---------------- MFMA GEMM1: H1f8[N,32 u32] = fp8(dinv * (X @ W1)), reads f32 X ----------------
// 4 waves/block, wave = 16 rows. lane l: row r0+(l&15), cols c*16 + lq*4 + q.
__global__ __launch_bounds__(256) void k_gemm1(const float* __restrict__ X,
                                               const unsigned short* __restrict__ Wpk,
                                               const float* __restrict__ dinv,
                                               unsigned* __restrict__ H1) {
    const int t = threadIdx.x;
    const int w = t >> 6, l = t & 63;
    const int row = blockIdx.x * 64 + w * 16 + (l & 15);
    const int rc = row < NN ? row : NN - 1;
    const int lq = l >> 4;
    f32x4 acc[8];
#pragma unroll
    for (int c = 0; c < 8; ++c) acc[c] = (f32x4){0.f, 0.f, 0.f, 0.f};
#pragma unroll
    for (int tt = 0; tt < 4; ++tt) {
        const float4* xp = (const float4*)(X + (size_t)rc * 128 + tt * 32 + lq * 8);
        float4 xa = xp[0], xb = xp[1];
        bf16x8 xf;
        unsigned* xu = (unsigned*)&xf;
        xu[0] = pack_bf16x2(xa.x, xa.y);
        xu[1] = pack_bf16x2(xa.z, xa.w);
        xu[2] = pack_bf16x2(xb.x, xb.y);
        xu[3] = pack_bf16x2(xb.z, xb.w);
#pragma unroll
        for (int c = 0; c < 8; ++c) {
            bf16x8 wf = *(const bf16x8*)(Wpk + (size_t)((c * 4 + tt) * 64 + l) * 8);
            acc[c] = __builtin_amdgcn_mfma_f32_16x16x32_bf16(wf, xf, acc[c], 0, 0, 0);
        }
    }
    if (row < NN) {
        float s = dinv[row];
        unsigned* orow = H1 + (size_t)row * 32;
#pragma unroll
        for (int c = 0; c < 8; ++c)
            orow[c * 4 + lq] = pack_fp8x4(acc[c][0] * s, acc[c][1] * s, acc[c][2] * s, acc[c][3] * s);
    }
}

// ---------------- MFMA GEMM2: H2f8[N,16 u32] = fp8(dinv * (X2 @ W2)) ----------------
__global__ __launch_bounds__(256) void k_gemm2(const unsigned short* __restrict__ Xb,
                                               const unsigned short* __restrict__ Wpk,
                                               const float* __restrict__ dinv,
                                               unsigned* __restrict__ H2) {
    const int t = threadIdx.x;
    const int w = t >> 6, l = t & 63;
    const int row = blockIdx.x * 64 + w * 16 + (l & 15);
    const int rc = row < NN ? row : NN - 1;
    const int lq = l >> 4;
    f32x4 acc[4];
#pragma unroll
    for (int c = 0; c < 4; ++c) acc[c] = (f32x4){0.f, 0.f, 0.f, 0.f};
#pragma unroll
    for (int tt = 0; tt < 4; ++tt) {
        bf16x8 xf = *(const bf16x8*)(Xb + (size_t)rc * 128 + tt * 32 + lq * 8);
#pragma unroll
        for (int c = 0; c < 4; ++c) {
            bf16x8 wf = *(const bf16x8*)(Wpk + (size_t)((c * 4 + tt) * 64 + l) * 8);
            acc[c] = __builtin_amdgcn_mfma_f32_16x16x32_bf16(wf, xf, acc[c], 0, 0, 0);
        }
    }
    if (row < NN) {
        float s = dinv[row];
        unsigned* orow = H2 + (size_t)row * 16;
#pragma unroll
        for (int c = 0; c < 4; ++c)
            orow[c * 4 + lq] = pack_fp8x4(acc[c][0] * s, acc[c][1] * s, acc[c][2] * s, acc[c][3] * s);
    }
}

// ---------------- layer-1 aggregate: quarter-wave, uint2/lane = full 128B fp8 row per load ----------------
__global__ void k_agg1(const int* __restrict__ row_start, const unsigned short* __restrict__ esrc,
                       const unsigned* __restrict__ H1, const float* __restrict__ dinv,
                       const float* __restrict__ b, unsigned* __restrict__ X2b) {
    int wid = (blockIdx.x * blockDim.x + threadIdx.x) >> 6;
    int lane = threadIdx.x & 63;
    if (wid >= NN) return;
    int beg = row_start[wid];
    int n = row_start[wid + 1] - beg;
    int q = lane >> 4, l16 = lane & 15;
    int qb = beg + ((n * q) >> 2);
    int qe = beg + ((n * (q + 1)) >> 2);
    const uint2* Hp = (const uint2*)H1;  // row = 16 uint2
    float a0 = 0.f, a1 = 0.f, a2 = 0.f, a3 = 0.f, a4 = 0.f, a5 = 0.f, a6 = 0.f, a7 = 0.f;
    int j = qb;
    for (; j + 4 <= qe; j += 4) {
        int s0 = esrc[j], s1 = esrc[j + 1], s2 = esrc[j + 2], s3 = esrc[j + 3];
        uint2 v0 = Hp[(size_t)s0 * 16 + l16];
        uint2 v1 = Hp[(size_t)s1 * 16 + l16];
        uint2 v2 = Hp[(size_t)s2 * 16 + l16];
        uint2 v3 = Hp[(size_t)s3 * 16 + l16];
#pragma unroll
        for (int k = 0; k < 4; ++k) {
            unsigned lo = (k == 0) ? v0.x : (k == 1) ? v1.x : (k == 2) ? v2.x : v3.x;
            unsigned hi = (k == 0) ? v0.y : (k == 1) ? v1.y : (k == 2) ? v2.y : v3.y;
            f32x2 p0 = __builtin_amdgcn_cvt_pk_f32_fp8(lo, false);
            f32x2 p1 = __builtin_amdgcn_cvt_pk_f32_fp8(lo, true);
            f32x2 p2 = __builtin_amdgcn_cvt_pk_f32_fp8(hi, false);
            f32x2 p3 = __builtin_amdgcn_cvt_pk_f32_fp8(hi, true);
            a0 += p0.x; a1 += p0.y; a2 += p1.x; a3 += p1.y;
            a4 += p2.x; a5 += p2.y; a6 += p3.x; a7 += p3.y;
        }
    }
    for (; j < qe; ++j) {
        uint2 v = Hp[(size_t)esrc[j] * 16 + l16];
        f32x2 p0 = __builtin_amdgcn_cvt_pk_f32_fp8(v.x, false);
        f32x2 p1 = __builtin_amdgcn_cvt_pk_f32_fp8(v.x, true);
        f32x2 p2 = __builtin_amdgcn_cvt_pk_f32_fp8(v.y, false);
        f32x2 p3 = __builtin_amdgcn_cvt_pk_f32_fp8(v.y, true);
        a0 += p0.x; a1 += p0.y; a2 += p1.x; a3 += p1.y;
        a4 += p2.x; a5 += p2.y; a6 += p3.x; a7 += p3.y;
    }
    if (q == 0) {  // self-loop, counted once
        uint2 v = Hp[(size_t)wid * 16 + l16];
        f32x2 p0 = __builtin_amdgcn_cvt_pk_f32_fp8(v.x, false);
        f32x2 p1 = __builtin_amdgcn_cvt_pk_f32_fp8(v.x, true);
        f32x2 p2 = __builtin_amdgcn_cvt_pk_f32_fp8(v.y, false);
        f32x2 p3 = __builtin_amdgcn_cvt_pk_f32_fp8(v.y, true);
        a0 += p0.x; a1 += p0.y; a2 += p1.x; a3 += p1.y;
        a4 += p2.x; a5 += p2.y; a6 += p3.x; a7 += p3.y;
    }
    a0 += __shfl_xor(a0, 16); a0 += __shfl_xor(a0, 32);
    a1 += __shfl_xor(a1, 16); a1 += __shfl_xor(a1, 32);
    a2 += __shfl_xor(a2, 16); a2 += __shfl_xor(a2, 32);
    a3 += __shfl_xor(a3, 16); a3 += __shfl_xor(a3, 32);
    a4 += __shfl_xor(a4, 16); a4 += __shfl_xor(a4, 32);
    a5 += __shfl_xor(a5, 16); a5 += __shfl_xor(a5, 32);
    a6 += __shfl_xor(a6, 16); a6 += __shfl_xor(a6, 32);
    a7 += __shfl_xor(a7, 16); a7 += __shfl_xor(a7, 32);
    if (q == 0) {
        float di = dinv[wid];
        float4 b0 = ((const float4*)b)[l16 * 2];
        float4 b1 = ((const float4*)b)[l16 * 2 + 1];
        uint4 st;
        st.x = pack_bf16x2(fmaxf(fmaf(di, a0, b0.x), 0.f), fmaxf(fmaf(di, a1, b0.y), 0.f));
        st.y = pack_bf16x2(fmaxf(fmaf(di, a2, b0.z), 0.f), fmaxf(fmaf(di, a3, b0.w), 0.f));
        st.z = pack_bf16x2(fmaxf(fmaf(di, a4, b1.x), 0.f), fmaxf(fmaf(di, a5, b1.y), 0.f));
        st.w = pack_bf16x2(fmaxf(fmaf(di, a6, b1.z), 0.f), fmaxf(fmaf(di, a7, b1.w), 0.f));
        ((uint4*)X2b)[(size_t)wid * 16 + l16] = st;
    }
}

// ---------------- layer-2 aggregate + log_softmax: quarter-wave, u32/lane = 64B fp8 row/load ----------------
__global__ void k_agg2_lsm(const int* __restrict__ row_start, const unsigned short* __restrict__ esrc,
                           const unsigned* __restrict__ H2, const float* __restrict__ dinv,
                           const float* __restrict__ b, float* __restrict__ OUT) {
    int wid = (blockIdx.x * blockDim.x + threadIdx.x) >> 6;
    int lane = threadIdx.x & 63;
    if (wid >= NN) return;
    int beg = row_start[wid];
    int n = row_start[wid + 1] - beg;
    int q = lane >> 4, l16 = lane & 15;
    int qb = beg + ((n * q) >> 2);
    int qe = beg + ((n * (q + 1)) >> 2);
    float a0 = 0.f, a1 = 0.f, a2 = 0.f, a3 = 0.f;
    int j = qb;
    for (; j + 4 <= qe; j += 4) {
        int s0 = esrc[j], s1 = esrc[j + 1], s2 = esrc[j + 2], s3 = esrc[j + 3];
        unsigned v0 = H2[(size_t)s0 * 16 + l16];
        unsigned v1 = H2[(size_t)s1 * 16 + l16];
        unsigned v2 = H2[(size_t)s2 * 16 + l16];
        unsigned v3 = H2[(size_t)s3 * 16 + l16];
#pragma unroll
        for (int k = 0; k < 4; ++k) {
            unsigned v = (k == 0) ? v0 : (k == 1) ? v1 : (k == 2) ? v2 : v3;
            f32x2 p0 = __builtin_amdgcn_cvt_pk_f32_fp8(v, false);
            f32x2 p1 = __builtin_amdgcn_cvt_pk_f32_fp8(v, true);
            a0 += p0.x; a1 += p0.y; a2 += p1.x; a3 += p1.y;
        }
    }
    for (; j < qe; ++j) {
        unsigned v = H2[(size_t)esrc[j] * 16 + l16];
        f32x2 p0 = __builtin_amdgcn_cvt_pk_f32_fp8(v, false);
        f32x2 p1 = __builtin_amdgcn_cvt_pk_f32_fp8(v, true);
        a0 += p0.x; a1 += p0.y; a2 += p1.x; a3 += p1.y;
    }
    if (q == 0) {  // self-loop
        unsigned v = H2[(size_t)wid * 16 + l16];
        f32x2 p0 = __builtin_amdgcn_cvt_pk_f32_fp8(v, false);
        f32x2 p1 = __builtin_amdgcn_cvt_pk_f32_fp8(v, true);
        a0 += p0.x; a1 += p0.y; a2 += p1.x; a3 += p1.y;
    }
    a0 += __shfl_xor(a0, 16); a0 += __shfl_xor(a0, 32);
    a1 += __shfl_xor(a1, 16); a1 += __shfl_xor(a1, 32);
    a2 += __shfl_xor(a2, 16); a2 += __shfl_xor(a2, 32);
    a3 += __shfl_xor(a3, 16); a3 += __shfl_xor(a3, 32);
    float di = dinv[wid];
    float4 bv = ((const float4*)b)[l16];
    float v0 = fmaf(di, a0, bv.x);
    float v1 = fmaf(di, a1, bv.y);
    float v2 = fmaf(di, a2, bv.z);
    float v3 = fmaf(di, a3, bv.w);
    float m = fmaxf(fmaxf(v0, v1), fmaxf(v2, v3));
#pragma unroll
    for (int o = 8; o > 0; o >>= 1) m = fmaxf(m, __shfl_xor(m, o));
    float s = expf(v0 - m) + expf(v1 - m) + expf(v2 - m) + expf(v3 - m);
#pragma unroll
    for (int o = 8; o > 0; o >>= 1) s += __shfl_xor(s, o);
    float ls = m + logf(s);
    if (q == 0) {
        float4 o4;
        o4.x = v0 - ls;
        o4.y = v1 - ls;
        o4.z = v2 - ls;
        o4.w = v3 - ls;
        ((float4*)OUT)[(size_t)wid * 16 + l16] = o4;
    }
}

extern "C" void kernel_launch(void* const* d_in, const int* in_sizes, int n_in,
                              void* d_out, int out_size, void* d_ws, size_t ws_size,
                              hipStream_t stream) {
    const float* x = (const float*)d_in[0];
    const int* ei = (const int*)d_in[1];  // [2, NE] int32
    const float* W1 = (const float*)d_in[2];
    const float* b1 = (const float*)d_in[3];
    const float* W2 = (const float*)d_in[4];
    const float* b2 = (const float*)d_in[5];
    float* out = (float*)d_out;

    const int* src = ei;
    const int* dst = ei + NE;

    // workspace layout (all segments 16B-aligned)
    int* bbase = (int*)d_ws;                                 // 400 (NB+1 used)
    int* bcur = bbase + 400;                                 // 400
    int* pbh = bcur + 400;                                   // NCH*NBP
    unsigned* eord = (unsigned*)(pbh + NCH * NBP);           // NE
    unsigned short* esrc16 = (unsigned short*)(eord + NE);   // NE
    int* row_start = (int*)(esrc16 + NE);                    // 50016
    float* dinv = (float*)(row_start + 50016);               // NN
    unsigned short* Wpk1 = (unsigned short*)(dinv + NN);     // 2048*8 bf16 (32KB)
    unsigned short* Wpk2 = Wpk1 + 2048 * 8;                  // 1024*8 bf16 (16KB)
    unsigned* H1f8 = (unsigned*)(Wpk2 + 1024 * 8);           // NN*32 u32 (fp8x4, 6.4MB)
    unsigned* H2f8 = H1f8 + (size_t)NN * 32;                 // NN*16 u32 (fp8x4, 3.2MB)
    unsigned* X2b = H2f8 + (size_t)NN * 16;                  // NN*64 u32 (bf16 row-major)

    k_hist<<<NCH + 12, 256, 0, stream>>>(dst, pbh, W1, W2, Wpk1, Wpk2);
    k_bscan<<<1, 512, 0, stream>>>(pbh, bbase, bcur);
    k_scat1<<<NCH, 256, 0, stream>>>(src, dst, bcur, eord);
    k_scat2<<<NB, 256, 0, stream>>>(bbase, eord, esrc16, row_start, dinv);

    // layer 1
    k_gemm1<<<(NN + 63) / 64, 256, 0, stream>>>(x, Wpk1, dinv, H1f8);
    k_agg1<<<(NN * 64 + 255) / 256, 256, 0, stream>>>(row_start, esrc16, H1f8, dinv, b1, X2b);
    // layer 2
    k_gemm2<<<(NN + 63) / 64, 256, 0, stream>>>((const unsigned short*)X2b, Wpk2, dinv, H2f8);
    k_agg2_lsm<<<(NN * 64 + 255) / 256, 256, 0, stream>>>(row_start, esrc16, H2f8, dinv, b2, out);
}

// Round 13
// 103.851 us; speedup vs baseline: 1.3376x; 1.1999x over previous
//
#include <hip/hip_runtime.h>

#define NN 50000
#define NE 800000
#define NB 391            // dst buckets of 128 nodes (391*128 = 50048)
#define NBP 392           // padded row stride for pbh
#define CHUNK 8192        // edges per pass-1 block
#define NCH ((NE + CHUNK - 1) / CHUNK)  // 98 blocks

typedef __attribute__((ext_vector_type(8))) short bf16x8;
typedef __attribute__((ext_vector_type(4))) float f32x4;
typedef __attribute__((ext_vector_type(2))) float f32x2;

__device__ __forceinline__ unsigned pack_bf16x2(float a, float b) {
    unsigned ua = __float_as_uint(a);
    unsigned ub = __float_as_uint(b);
    ua = (ua + 0x7FFFu + ((ua >> 16) & 1u)) >> 16;
    ub = (ub + 0x7FFFu + ((ub >> 16) & 1u)) >> 16;
    return ua | (ub << 16);
}
// pack 4 floats -> 4 fp8 e4m3 (one u32)
__device__ __forceinline__ unsigned pack_fp8x4(float a, float b, float c, float d) {
    int w = __builtin_amdgcn_cvt_pk_fp8_f32(a, b, 0, false);
    w = __builtin_amdgcn_cvt_pk_fp8_f32(c, d, w, true);
    return (unsigned)w;
}
// decode 8 fp8 (two u32) and accumulate into a[0..7]
__device__ __forceinline__ void dec8(unsigned lo, unsigned hi, float* a) {
    f32x2 p0 = __builtin_amdgcn_cvt_pk_f32_fp8(lo, false);
    f32x2 p1 = __builtin_amdgcn_cvt_pk_f32_fp8(lo, true);
    f32x2 p2 = __builtin_amdgcn_cvt_pk_f32_fp8(hi, false);
    f32x2 p3 = __builtin_amdgcn_cvt_pk_f32_fp8(hi, true);
    a[0] += p0.x; a[1] += p0.y; a[2] += p1.x; a[3] += p1.y;
    a[4] += p2.x; a[5] += p2.y; a[6] += p3.x; a[7] += p3.y;
}

// ---------------- fused prep: per-chunk bucket histogram + W pack ----------------
__global__ void k_hist(const int* __restrict__ dst, int* __restrict__ pbh,
                       const float* __restrict__ W1, const float* __restrict__ W2,
                       unsigned short* __restrict__ Wpk1, unsigned short* __restrict__ Wpk2) {
    const int t = threadIdx.x;
    if (blockIdx.x >= NCH) {  // W-pack part
        int gid = (blockIdx.x - NCH) * 256 + t;
        const float* W;
        unsigned short* Wpk;
        int idx, M;
        if (gid < 2048) { W = W1; Wpk = Wpk1; idx = gid; M = 128; }
        else if (gid < 3072) { W = W2; Wpk = Wpk2; idx = gid - 2048; M = 64; }
        else return;
        int l = idx & 63;
        int tt = (idx >> 6) & 3;
        int ct = idx >> 8;
        int col = ct * 16 + (l & 15);
        int k0 = tt * 32 + (l >> 4) * 8;
        unsigned* o = (unsigned*)(Wpk + (size_t)idx * 8);
#pragma unroll
        for (int j = 0; j < 8; j += 2)
            o[j >> 1] = pack_bf16x2(W[(size_t)(k0 + j) * M + col], W[(size_t)(k0 + j + 1) * M + col]);
        return;
    }
    __shared__ int h[NB];
    for (int j = t; j < NB; j += 256) h[j] = 0;
    __syncthreads();
    const int e0 = blockIdx.x * CHUNK;
#pragma unroll 8
    for (int i = 0; i < 32; ++i) {
        int e = e0 + t + i * 256;
        if (e < NE) atomicAdd(&h[dst[e] >> 7], 1);
    }
    __syncthreads();
    for (int j = t; j < NB; j += 256) pbh[blockIdx.x * NBP + j] = h[j];
}

// ---------------- bucket totals + exclusive scan -> bbase, bcur ----------------
__global__ void k_bscan(const int* __restrict__ pbh, int* __restrict__ bbase,
                        int* __restrict__ bcur) {
    __shared__ int s[512];
    const int t = threadIdx.x;
    int tot = 0;
    if (t < NB) {
        int c = 0;
        for (; c + 4 <= NCH; c += 4)
            tot += pbh[c * NBP + t] + pbh[(c + 1) * NBP + t] +
                   pbh[(c + 2) * NBP + t] + pbh[(c + 3) * NBP + t];
        for (; c < NCH; ++c) tot += pbh[c * NBP + t];
    }
    s[t] = (t < NB) ? tot : 0;
    __syncthreads();
    for (int o = 1; o < 512; o <<= 1) {
        int a = (t >= o) ? s[t - o] : 0;
        __syncthreads();
        s[t] += a;
        __syncthreads();
    }
    int ex = s[t] - tot;
    if (t < NB) {
        bbase[t] = ex;
        bcur[t] = ex;
    }
    if (t == 0) bbase[NB] = NE;
}

// ---------------- pass 1: bucket-bin edges (block reserves ranges via bcur atomics) ----------------
// packed edge: [31:16]=dst, [15:0]=src ; bucket = pk>>23
__global__ void k_scat1(const int* __restrict__ src, const int* __restrict__ dst,
                        int* __restrict__ bcur, unsigned* __restrict__ eord) {
    __shared__ int hist[NB];
    __shared__ int gbase[NB];
    const int t = threadIdx.x;
    const int e0 = blockIdx.x * CHUNK;
    for (int j = t; j < NB; j += 256) hist[j] = 0;
    __syncthreads();
    unsigned pk[32];
#pragma unroll
    for (int i = 0; i < 32; ++i) {
        int e = e0 + t + i * 256;
        pk[i] = 0xFFFFFFFFu;
        if (e < NE) {
            unsigned s = (unsigned)src[e];
            unsigned d = (unsigned)dst[e];
            pk[i] = (d << 16) | s;
            atomicAdd(&hist[d >> 7], 1);
        }
    }
    __syncthreads();
    for (int j = t; j < NB; j += 256) {
        int c = hist[j];
        gbase[j] = c ? atomicAdd(&bcur[j], c) : 0;
        hist[j] = 0;  // reuse as within-block cursor
    }
    __syncthreads();
#pragma unroll
    for (int i = 0; i < 32; ++i) {
        if (pk[i] != 0xFFFFFFFFu) {
            int bk = pk[i] >> 23;
            int pos = gbase[bk] + atomicAdd(&hist[bk], 1);
            eord[pos] = pk[i];
        }
    }
}

// ---------------- pass 2: within-bucket sort + row_start + dinv ----------------
__global__ void k_scat2(const int* __restrict__ bbase, const unsigned* __restrict__ eord,
                        unsigned short* __restrict__ esrc16, int* __restrict__ row_start,
                        float* __restrict__ dinv) {
    __shared__ int cnt[128];
    __shared__ int pre[128];
    __shared__ int cur[128];
    const int b = blockIdx.x, t = threadIdx.x, d0 = b << 7;
    if (t < 128) cnt[t] = 0;
    __syncthreads();
    const int beg = bbase[b], end = bbase[b + 1];
    for (int i = beg + t; i < end; i += 256) atomicAdd(&cnt[(eord[i] >> 16) & 127], 1);
    __syncthreads();
    int v = (t < 128) ? cnt[t] : 0;
    if (t < 128) pre[t] = v;
    __syncthreads();
    for (int o = 1; o < 128; o <<= 1) {
        int a = (t < 128 && t >= o) ? pre[t - o] : 0;
        __syncthreads();
        if (t < 128) pre[t] += a;
        __syncthreads();
    }
    if (t < 128) {
        int ex = beg + pre[t] - v;
        int d = d0 + t;
        if (d < NN) {
            row_start[d] = ex;
            dinv[d] = rsqrtf((float)(v + 1));  // +1 self-loop
        }
        cur[t] = ex;
    }
    if (b == NB - 1 && t == 0) row_start[NN] = NE;
    __syncthreads();
    for (int i = beg + t; i < end; i += 256) {
        unsigned x = eord[i];
        int pos = atomicAdd(&cur[(x >> 16) & 127], 1);
        esrc16[pos] = (unsigned short)(x & 0xFFFFu);
    }
}

// ---------------- MFMA GEMM1: H1f8[N,32 u32] = fp8(dinv * (X @ W1)), reads f32 X ----------------
__global__ __launch_bounds__(256) void k_gemm1(const float* __restrict__ X,
                                               const unsigned short* __restrict__ Wpk,
                                               const float* __restrict__ dinv,
                                               unsigned* __restrict__ H1) {
    const int t = threadIdx.x;
    const int w = t >> 6, l = t & 63;
    const int row = blockIdx.x * 64 + w * 16 + (l & 15);
    const int rc = row < NN ? row : NN - 1;
    const int lq = l >> 4;
    f32x4 acc[8];
#pragma unroll
    for (int c = 0; c < 8; ++c) acc[c] = (f32x4){0.f, 0.f, 0.f, 0.f};
#pragma unroll
    for (int tt = 0; tt < 4; ++tt) {
        const float4* xp = (const float4*)(X + (size_t)rc * 128 + tt * 32 + lq * 8);
        float4 xa = xp[0], xb = xp[1];
        bf16x8 xf;
        unsigned* xu = (unsigned*)&xf;
        xu[0] = pack_bf16x2(xa.x, xa.y);
        xu[1] = pack_bf16x2(xa.z, xa.w);
        xu[2] = pack_bf16x2(xb.x, xb.y);
        xu[3] = pack_bf16x2(xb.z, xb.w);
#pragma unroll
        for (int c = 0; c < 8; ++c) {
            bf16x8 wf = *(const bf16x8*)(Wpk + (size_t)((c * 4 + tt) * 64 + l) * 8);
            acc[c] = __builtin_amdgcn_mfma_f32_16x16x32_bf16(wf, xf, acc[c], 0, 0, 0);
        }
    }
    if (row < NN) {
        float s = dinv[row];
        unsigned* orow = H1 + (size_t)row * 32;
#pragma unroll
        for (int c = 0; c < 8; ++c)
            orow[c * 4 + lq] = pack_fp8x4(acc[c][0] * s, acc[c][1] * s, acc[c][2] * s, acc[c][3] * s);
    }
}

// ---------------- MFMA GEMM2: H2f8[N,16 u32] = fp8(dinv * (X2 @ W2)) ----------------
__global__ __launch_bounds__(256) void k_gemm2(const unsigned short* __restrict__ Xb,
                                               const unsigned short* __restrict__ Wpk,
                                               const float* __restrict__ dinv,
                                               unsigned* __restrict__ H2) {
    const int t = threadIdx.x;
    const int w = t >> 6, l = t & 63;
    const int row = blockIdx.x * 64 + w * 16 + (l & 15);
    const int rc = row < NN ? row : NN - 1;
    const int lq = l >> 4;
    f32x4 acc[4];
#pragma unroll
    for (int c = 0; c < 4; ++c) acc[c] = (f32x4){0.f, 0.f, 0.f, 0.f};
#pragma unroll
    for (int tt = 0; tt < 4; ++tt) {
        bf16x8 xf = *(const bf16x8*)(Xb + (size_t)rc * 128 + tt * 32 + lq * 8);
#pragma unroll
        for (int c = 0; c < 4; ++c) {
            bf16x8 wf = *(const bf16x8*)(Wpk + (size_t)((c * 4 + tt) * 64 + l) * 8);
            acc[c] = __builtin_amdgcn_mfma_f32_16x16x32_bf16(wf, xf, acc[c], 0, 0, 0);
        }
    }
    if (row < NN) {
        float s = dinv[row];
        unsigned* orow = H2 + (size_t)row * 16;
#pragma unroll
        for (int c = 0; c < 4; ++c)
            orow[c * 4 + lq] = pack_fp8x4(acc[c][0] * s, acc[c][1] * s, acc[c][2] * s, acc[c][3] * s);
    }
}

// ---------------- layer-1 aggregate: 8-lane group per node, uint4/lane (16 cols) ----------------
// One wave-load gathers 8 edges' half-rows (8 groups x 16B). No cross-lane reduces.
__global__ void k_agg1(const int* __restrict__ row_start, const unsigned short* __restrict__ esrc,
                       const unsigned* __restrict__ H1, const float* __restrict__ dinv,
                       const float* __restrict__ b, unsigned* __restrict__ X2b) {
    int wave = (blockIdx.x * blockDim.x + threadIdx.x) >> 6;
    int lane = threadIdx.x & 63;
    int g = lane >> 3, gl = lane & 7;
    int wid = wave * 8 + g;
    if (wid >= NN) return;
    int beg = row_start[wid];
    int n = row_start[wid + 1] - beg;
    const uint4* Hp = (const uint4*)H1;  // row = 8 uint4
    float a[16];
#pragma unroll
    for (int k = 0; k < 16; ++k) a[k] = 0.f;
    int j = 0;
    for (; j + 4 <= n; j += 4) {
        int s0 = esrc[beg + j], s1 = esrc[beg + j + 1];
        int s2 = esrc[beg + j + 2], s3 = esrc[beg + j + 3];
        uint4 v0 = Hp[(size_t)s0 * 8 + gl];
        uint4 v1 = Hp[(size_t)s1 * 8 + gl];
        uint4 v2 = Hp[(size_t)s2 * 8 + gl];
        uint4 v3 = Hp[(size_t)s3 * 8 + gl];
        dec8(v0.x, v0.y, a); dec8(v0.z, v0.w, a + 8);
        dec8(v1.x, v1.y, a); dec8(v1.z, v1.w, a + 8);
        dec8(v2.x, v2.y, a); dec8(v2.z, v2.w, a + 8);
        dec8(v3.x, v3.y, a); dec8(v3.z, v3.w, a + 8);
    }
    for (; j < n; ++j) {
        uint4 v = Hp[(size_t)esrc[beg + j] * 8 + gl];
        dec8(v.x, v.y, a); dec8(v.z, v.w, a + 8);
    }
    {   // self-loop, whole group adds once
        uint4 v = Hp[(size_t)wid * 8 + gl];
        dec8(v.x, v.y, a); dec8(v.z, v.w, a + 8);
    }
    float di = dinv[wid];
    const float4* bp = (const float4*)b;  // 16 bias floats for this lane
    float r[16];
#pragma unroll
    for (int kq = 0; kq < 4; ++kq) {
        float4 bv = bp[gl * 4 + kq];
        r[kq * 4 + 0] = fmaxf(fmaf(di, a[kq * 4 + 0], bv.x), 0.f);
        r[kq * 4 + 1] = fmaxf(fmaf(di, a[kq * 4 + 1], bv.y), 0.f);
        r[kq * 4 + 2] = fmaxf(fmaf(di, a[kq * 4 + 2], bv.z), 0.f);
        r[kq * 4 + 3] = fmaxf(fmaf(di, a[kq * 4 + 3], bv.w), 0.f);
    }
    uint4 st0, st1;
    st0.x = pack_bf16x2(r[0], r[1]);  st0.y = pack_bf16x2(r[2], r[3]);
    st0.z = pack_bf16x2(r[4], r[5]);  st0.w = pack_bf16x2(r[6], r[7]);
    st1.x = pack_bf16x2(r[8], r[9]);  st1.y = pack_bf16x2(r[10], r[11]);
    st1.z = pack_bf16x2(r[12], r[13]); st1.w = pack_bf16x2(r[14], r[15]);
    ((uint4*)X2b)[(size_t)wid * 16 + gl * 2] = st0;
    ((uint4*)X2b)[(size_t)wid * 16 + gl * 2 + 1] = st1;
}

// ---------------- layer-2 aggregate + log_softmax: 8-lane group per node, uint2/lane ----------------
__global__ void k_agg2_lsm(const int* __restrict__ row_start, const unsigned short* __restrict__ esrc,
                           const unsigned* __restrict__ H2, const float* __restrict__ dinv,
                           const float* __restrict__ b, float* __restrict__ OUT) {
    int wave = (blockIdx.x * blockDim.x + threadIdx.x) >> 6;
    int lane = threadIdx.x & 63;
    int g = lane >> 3, gl = lane & 7;
    int wid = wave * 8 + g;
    if (wid >= NN) return;
    int beg = row_start[wid];
    int n = row_start[wid + 1] - beg;
    const uint2* Hp = (const uint2*)H2;  // row = 8 uint2
    float a[8];
#pragma unroll
    for (int k = 0; k < 8; ++k) a[k] = 0.f;
    int j = 0;
    for (; j + 4 <= n; j += 4) {
        int s0 = esrc[beg + j], s1 = esrc[beg + j + 1];
        int s2 = esrc[beg + j + 2], s3 = esrc[beg + j + 3];
        uint2 v0 = Hp[(size_t)s0 * 8 + gl];
        uint2 v1 = Hp[(size_t)s1 * 8 + gl];
        uint2 v2 = Hp[(size_t)s2 * 8 + gl];
        uint2 v3 = Hp[(size_t)s3 * 8 + gl];
        dec8(v0.x, v0.y, a);
        dec8(v1.x, v1.y, a);
        dec8(v2.x, v2.y, a);
        dec8(v3.x, v3.y, a);
    }
    for (; j < n; ++j) {
        uint2 v = Hp[(size_t)esrc[beg + j] * 8 + gl];
        dec8(v.x, v.y, a);
    }
    {   // self-loop
        uint2 v = Hp[(size_t)wid * 8 + gl];
        dec8(v.x, v.y, a);
    }
    float di = dinv[wid];
    float v[8];
    const float4* bp = (const float4*)b;
#pragma unroll
    for (int kq = 0; kq < 2; ++kq) {
        float4 bv = bp[gl * 2 + kq];
        v[kq * 4 + 0] = fmaf(di, a[kq * 4 + 0], bv.x);
        v[kq * 4 + 1] = fmaf(di, a[kq * 4 + 1], bv.y);
        v[kq * 4 + 2] = fmaf(di, a[kq * 4 + 2], bv.z);
        v[kq * 4 + 3] = fmaf(di, a[kq * 4 + 3], bv.w);
    }
    float m = v[0];
#pragma unroll
    for (int k = 1; k < 8; ++k) m = fmaxf(m, v[k]);
#pragma unroll
    for (int o = 1; o < 8; o <<= 1) m = fmaxf(m, __shfl_xor(m, o));
    float s = 0.f;
#pragma unroll
    for (int k = 0; k < 8; ++k) s += expf(v[k] - m);
#pragma unroll
    for (int o = 1; o < 8; o <<= 1) s += __shfl_xor(s, o);
    float ls = m + logf(s);
    float4 o0, o1;
    o0.x = v[0] - ls; o0.y = v[1] - ls; o0.z = v[2] - ls; o0.w = v[3] - ls;
    o1.x = v[4] - ls; o1.y = v[5] - ls; o1.z = v[6] - ls; o1.w = v[7] - ls;
    ((float4*)OUT)[(size_t)wid * 16 + gl * 2] = o0;
    ((float4*)OUT)[(size_t)wid * 16 + gl * 2 + 1] = o1;
}

extern "C" void kernel_launch(void* const* d_in, const int* in_sizes, int n_in,
                              void* d_out, int out_size, void* d_ws, size_t ws_size,
                              hipStream_t stream) {
    const float* x = (const float*)d_in[0];
    const int* ei = (const int*)d_in[1];  // [2, NE] int32
    const float* W1 = (const float*)d_in[2];
    const float* b1 = (const float*)d_in[3];
    const float* W2 = (const float*)d_in[4];
    const float* b2 = (const float*)d_in[5];
    float* out = (float*)d_out;

    const int* src = ei;
    const int* dst = ei + NE;

    // workspace layout (all segments 16B-aligned)
    int* bbase = (int*)d_ws;                                 // 400 (NB+1 used)
    int* bcur = bbase + 400;                                 // 400
    int* pbh = bcur + 400;                                   // NCH*NBP
    unsigned* eord = (unsigned*)(pbh + NCH * NBP);           // NE
    unsigned short* esrc16 = (unsigned short*)(eord + NE);   // NE
    int* row_start = (int*)(esrc16 + NE);                    // 50016
    float* dinv = (float*)(row_start + 50016);               // NN
    unsigned short* Wpk1 = (unsigned short*)(dinv + NN);     // 2048*8 bf16 (32KB)
    unsigned short* Wpk2 = Wpk1 + 2048 * 8;                  // 1024*8 bf16 (16KB)
    unsigned* H1f8 = (unsigned*)(Wpk2 + 1024 * 8);           // NN*32 u32 (fp8x4, 6.4MB)
    unsigned* H2f8 = H1f8 + (size_t)NN * 32;                 // NN*16 u32 (fp8x4, 3.2MB)
    unsigned* X2b = H2f8 + (size_t)NN * 16;                  // NN*64 u32 (bf16 row-major)

    k_hist<<<NCH + 12, 256, 0, stream>>>(dst, pbh, W1, W2, Wpk1, Wpk2);
    k_bscan<<<1, 512, 0, stream>>>(pbh, bbase, bcur);
    k_scat1<<<NCH, 256, 0, stream>>>(src, dst, bcur, eord);
    k_scat2<<<NB, 256, 0, stream>>>(bbase, eord, esrc16, row_start, dinv);

    const int aggBlocks = (((NN + 7) / 8) * 64 + 255) / 256;
    // layer 1
    k_gemm1<<<(NN + 63) / 64, 256, 0, stream>>>(x, Wpk1, dinv, H1f8);
    k_agg1<<<aggBlocks, 256, 0, stream>>>(row_start, esrc16, H1f8, dinv, b1, X2b);
    // layer 2
    k_gemm2<<<(NN + 63) / 64, 256, 0, stream>>>((const unsigned short*)X2b, Wpk2, dinv, H2f8);
    k_agg2_lsm<<<aggBlocks, 256, 0, stream>>>(row_start, esrc16, H2f8, dinv, b2, out);
}

// Round 14
// 99.693 us; speedup vs baseline: 1.3934x; 1.0417x over previous
//
#include <hip/hip_runtime.h>

#define NN 50000
#define NE 800000
#define NB 391            // dst buckets of 128 nodes (391*128 = 50048)
#define NBP 392           // padded row stride for pbh
#define CHUNK 8192        // edges per pass-1 block
#define NCH ((NE + CHUNK - 1) / CHUNK)  // 98 blocks

typedef __attribute__((ext_vector_type(8))) short bf16x8;
typedef __attribute__((ext_vector_type(4))) float f32x4;
typedef __attribute__((ext_vector_type(2))) float f32x2;

__device__ __forceinline__ unsigned pack_bf16x2(float a, float b) {
    unsigned ua = __float_as_uint(a);
    unsigned ub = __float_as_uint(b);
    ua = (ua + 0x7FFFu + ((ua >> 16) & 1u)) >> 16;
    ub = (ub + 0x7FFFu + ((ub >> 16) & 1u)) >> 16;
    return ua | (ub << 16);
}
// pack 4 floats -> 4 fp8 e4m3 (one u32)
__device__ __forceinline__ unsigned pack_fp8x4(float a, float b, float c, float d) {
    int w = __builtin_amdgcn_cvt_pk_fp8_f32(a, b, 0, false);
    w = __builtin_amdgcn_cvt_pk_fp8_f32(c, d, w, true);
    return (unsigned)w;
}
// decode 8 fp8 (two u32) and accumulate into a[0..7]
__device__ __forceinline__ void dec8(unsigned lo, unsigned hi, float* a) {
    f32x2 p0 = __builtin_amdgcn_cvt_pk_f32_fp8(lo, false);
    f32x2 p1 = __builtin_amdgcn_cvt_pk_f32_fp8(lo, true);
    f32x2 p2 = __builtin_amdgcn_cvt_pk_f32_fp8(hi, false);
    f32x2 p3 = __builtin_amdgcn_cvt_pk_f32_fp8(hi, true);
    a[0] += p0.x; a[1] += p0.y; a[2] += p1.x; a[3] += p1.y;
    a[4] += p2.x; a[5] += p2.y; a[6] += p3.x; a[7] += p3.y;
}

// ---------------- fused prep: per-chunk bucket histogram + W pack ----------------
__global__ void k_hist(const int* __restrict__ dst, int* __restrict__ pbh,
                       const float* __restrict__ W1, const float* __restrict__ W2,
                       unsigned short* __restrict__ Wpk1, unsigned short* __restrict__ Wpk2) {
    const int t = threadIdx.x;
    if (blockIdx.x >= NCH) {  // W-pack part
        int gid = (blockIdx.x - NCH) * 256 + t;
        const float* W;
        unsigned short* Wpk;
        int idx, M;
        if (gid < 2048) { W = W1; Wpk = Wpk1; idx = gid; M = 128; }
        else if (gid < 3072) { W = W2; Wpk = Wpk2; idx = gid - 2048; M = 64; }
        else return;
        int l = idx & 63;
        int tt = (idx >> 6) & 3;
        int ct = idx >> 8;
        int col = ct * 16 + (l & 15);
        int k0 = tt * 32 + (l >> 4) * 8;
        unsigned* o = (unsigned*)(Wpk + (size_t)idx * 8);
#pragma unroll
        for (int j = 0; j < 8; j += 2)
            o[j >> 1] = pack_bf16x2(W[(size_t)(k0 + j) * M + col], W[(size_t)(k0 + j + 1) * M + col]);
        return;
    }
    __shared__ int h[NB];
    for (int j = t; j < NB; j += 256) h[j] = 0;
    __syncthreads();
    const int e0 = blockIdx.x * CHUNK;
#pragma unroll 8
    for (int i = 0; i < 32; ++i) {
        int e = e0 + t + i * 256;
        if (e < NE) atomicAdd(&h[dst[e] >> 7], 1);
    }
    __syncthreads();
    for (int j = t; j < NB; j += 256) pbh[blockIdx.x * NBP + j] = h[j];
}

// ---------------- bucket totals + exclusive scan -> bbase, bcur ----------------
__global__ void k_bscan(const int* __restrict__ pbh, int* __restrict__ bbase,
                        int* __restrict__ bcur) {
    __shared__ int s[512];
    const int t = threadIdx.x;
    int tot = 0;
    if (t < NB) {
        int c = 0;
        for (; c + 4 <= NCH; c += 4)
            tot += pbh[c * NBP + t] + pbh[(c + 1) * NBP + t] +
                   pbh[(c + 2) * NBP + t] + pbh[(c + 3) * NBP + t];
        for (; c < NCH; ++c) tot += pbh[c * NBP + t];
    }
    s[t] = (t < NB) ? tot : 0;
    __syncthreads();
    for (int o = 1; o < 512; o <<= 1) {
        int a = (t >= o) ? s[t - o] : 0;
        __syncthreads();
        s[t] += a;
        __syncthreads();
    }
    int ex = s[t] - tot;
    if (t < NB) {
        bbase[t] = ex;
        bcur[t] = ex;
    }
    if (t == 0) bbase[NB] = NE;
}

// ---------------- pass 1: bucket-bin edges (block reserves ranges via bcur atomics) ----------------
__global__ void k_scat1(const int* __restrict__ src, const int* __restrict__ dst,
                        int* __restrict__ bcur, unsigned* __restrict__ eord) {
    __shared__ int hist[NB];
    __shared__ int gbase[NB];
    const int t = threadIdx.x;
    const int e0 = blockIdx.x * CHUNK;
    for (int j = t; j < NB; j += 256) hist[j] = 0;
    __syncthreads();
    unsigned pk[32];
#pragma unroll
    for (int i = 0; i < 32; ++i) {
        int e = e0 + t + i * 256;
        pk[i] = 0xFFFFFFFFu;
        if (e < NE) {
            unsigned s = (unsigned)src[e];
            unsigned d = (unsigned)dst[e];
            pk[i] = (d << 16) | s;
            atomicAdd(&hist[d >> 7], 1);
        }
    }
    __syncthreads();
    for (int j = t; j < NB; j += 256) {
        int c = hist[j];
        gbase[j] = c ? atomicAdd(&bcur[j], c) : 0;
        hist[j] = 0;  // reuse as within-block cursor
    }
    __syncthreads();
#pragma unroll
    for (int i = 0; i < 32; ++i) {
        if (pk[i] != 0xFFFFFFFFu) {
            int bk = pk[i] >> 23;
            int pos = gbase[bk] + atomicAdd(&hist[bk], 1);
            eord[pos] = pk[i];
        }
    }
}

// ---------------- pass 2: within-bucket sort + row_start + dinv (single eord read) ----------------
__global__ void k_scat2(const int* __restrict__ bbase, const unsigned* __restrict__ eord,
                        unsigned short* __restrict__ esrc16, int* __restrict__ row_start,
                        float* __restrict__ dinv) {
    __shared__ int cnt[128];
    __shared__ int pre[128];
    __shared__ int cur[128];
    const int b = blockIdx.x, t = threadIdx.x, d0 = b << 7;
    if (t < 128) cnt[t] = 0;
    __syncthreads();
    const int beg = bbase[b], end = bbase[b + 1];
    unsigned pk[12];
#pragma unroll
    for (int it = 0; it < 12; ++it) {
        int i = beg + t + it * 256;
        if (i < end) {
            pk[it] = eord[i];
            atomicAdd(&cnt[(pk[it] >> 16) & 127], 1);
        }
    }
    for (int i = beg + t + 12 * 256; i < end; i += 256)  // overflow fallback (never at E/NB~2046)
        atomicAdd(&cnt[(eord[i] >> 16) & 127], 1);
    __syncthreads();
    int v = (t < 128) ? cnt[t] : 0;
    if (t < 128) pre[t] = v;
    __syncthreads();
    for (int o = 1; o < 128; o <<= 1) {
        int a = (t < 128 && t >= o) ? pre[t - o] : 0;
        __syncthreads();
        if (t < 128) pre[t] += a;
        __syncthreads();
    }
    if (t < 128) {
        int ex = beg + pre[t] - v;
        int d = d0 + t;
        if (d < NN) {
            row_start[d] = ex;
            dinv[d] = rsqrtf((float)(v + 1));  // +1 self-loop
        }
        cur[t] = ex;
    }
    if (b == NB - 1 && t == 0) row_start[NN] = NE;
    __syncthreads();
#pragma unroll
    for (int it = 0; it < 12; ++it) {
        int i = beg + t + it * 256;
        if (i < end) {
            int pos = atomicAdd(&cur[(pk[it] >> 16) & 127], 1);
            esrc16[pos] = (unsigned short)(pk[it] & 0xFFFFu);
        }
    }
    for (int i = beg + t + 12 * 256; i < end; i += 256) {
        unsigned x = eord[i];
        int pos = atomicAdd(&cur[(x >> 16) & 127], 1);
        esrc16[pos] = (unsigned short)(x & 0xFFFFu);
    }
}

// ---------------- MFMA GEMM1: H1f8[N,32 u32] = fp8(dinv * (X @ W1)), reads f32 X ----------------
__global__ __launch_bounds__(256) void k_gemm1(const float* __restrict__ X,
                                               const unsigned short* __restrict__ Wpk,
                                               const float* __restrict__ dinv,
                                               unsigned* __restrict__ H1) {
    const int t = threadIdx.x;
    const int w = t >> 6, l = t & 63;
    const int row = blockIdx.x * 64 + w * 16 + (l & 15);
    const int rc = row < NN ? row : NN - 1;
    const int lq = l >> 4;
    f32x4 acc[8];
#pragma unroll
    for (int c = 0; c < 8; ++c) acc[c] = (f32x4){0.f, 0.f, 0.f, 0.f};
#pragma unroll
    for (int tt = 0; tt < 4; ++tt) {
        const float4* xp = (const float4*)(X + (size_t)rc * 128 + tt * 32 + lq * 8);
        float4 xa = xp[0], xb = xp[1];
        bf16x8 xf;
        unsigned* xu = (unsigned*)&xf;
        xu[0] = pack_bf16x2(xa.x, xa.y);
        xu[1] = pack_bf16x2(xa.z, xa.w);
        xu[2] = pack_bf16x2(xb.x, xb.y);
        xu[3] = pack_bf16x2(xb.z, xb.w);
#pragma unroll
        for (int c = 0; c < 8; ++c) {
            bf16x8 wf = *(const bf16x8*)(Wpk + (size_t)((c * 4 + tt) * 64 + l) * 8);
            acc[c] = __builtin_amdgcn_mfma_f32_16x16x32_bf16(wf, xf, acc[c], 0, 0, 0);
        }
    }
    if (row < NN) {
        float s = dinv[row];
        unsigned* orow = H1 + (size_t)row * 32;
#pragma unroll
        for (int c = 0; c < 8; ++c)
            orow[c * 4 + lq] = pack_fp8x4(acc[c][0] * s, acc[c][1] * s, acc[c][2] * s, acc[c][3] * s);
    }
}

// ---------------- FUSED layer-1 aggregate + GEMM2 ----------------
// Phase A: 8-lane group per node (32 nodes/block), X2 row -> registers -> LDS bf16.
// Phase B: 4 waves do MFMA (X2[32,128] @ W2[128,64]) -> fp8 H2, no global X2.
__global__ __launch_bounds__(256) void k_agg1g2(const int* __restrict__ row_start,
                                                const unsigned short* __restrict__ esrc,
                                                const unsigned* __restrict__ H1,
                                                const float* __restrict__ dinv,
                                                const float* __restrict__ b1,
                                                const unsigned short* __restrict__ Wpk2,
                                                unsigned* __restrict__ H2) {
    __shared__ unsigned x2[32][68];  // 32 nodes x 128 bf16 (u32 pairs), stride 68 -> 2-way-free banks
    const int t = threadIdx.x;
    const int w = t >> 6, lane = t & 63;
    const int g = lane >> 3, gl = lane & 7;
    const int nbase = blockIdx.x * 32;
    const int wid = nbase + w * 8 + g;
    float a[16];
#pragma unroll
    for (int k = 0; k < 16; ++k) a[k] = 0.f;
    if (wid < NN) {
        int beg = row_start[wid];
        int n = row_start[wid + 1] - beg;
        const uint4* Hp = (const uint4*)H1;  // row = 8 uint4
        int j = 0;
        for (; j + 4 <= n; j += 4) {
            int s0 = esrc[beg + j], s1 = esrc[beg + j + 1];
            int s2 = esrc[beg + j + 2], s3 = esrc[beg + j + 3];
            uint4 v0 = Hp[(size_t)s0 * 8 + gl];
            uint4 v1 = Hp[(size_t)s1 * 8 + gl];
            uint4 v2 = Hp[(size_t)s2 * 8 + gl];
            uint4 v3 = Hp[(size_t)s3 * 8 + gl];
            dec8(v0.x, v0.y, a); dec8(v0.z, v0.w, a + 8);
            dec8(v1.x, v1.y, a); dec8(v1.z, v1.w, a + 8);
            dec8(v2.x, v2.y, a); dec8(v2.z, v2.w, a + 8);
            dec8(v3.x, v3.y, a); dec8(v3.z, v3.w, a + 8);
        }
        for (; j < n; ++j) {
            uint4 v = Hp[(size_t)esrc[beg + j] * 8 + gl];
            dec8(v.x, v.y, a); dec8(v.z, v.w, a + 8);
        }
        {   // self-loop
            uint4 v = Hp[(size_t)wid * 8 + gl];
            dec8(v.x, v.y, a); dec8(v.z, v.w, a + 8);
        }
        float di = dinv[wid];
        const float4* bp = (const float4*)b1;
#pragma unroll
        for (int kq = 0; kq < 4; ++kq) {
            float4 bv = bp[gl * 4 + kq];
            a[kq * 4 + 0] = fmaxf(fmaf(di, a[kq * 4 + 0], bv.x), 0.f);
            a[kq * 4 + 1] = fmaxf(fmaf(di, a[kq * 4 + 1], bv.y), 0.f);
            a[kq * 4 + 2] = fmaxf(fmaf(di, a[kq * 4 + 2], bv.z), 0.f);
            a[kq * 4 + 3] = fmaxf(fmaf(di, a[kq * 4 + 3], bv.w), 0.f);
        }
    }
    {   // stage X2 row (bf16) to LDS
        const int nl = w * 8 + g;
        unsigned* row = &x2[nl][gl * 8];
        row[0] = pack_bf16x2(a[0], a[1]);
        row[1] = pack_bf16x2(a[2], a[3]);
        row[2] = pack_bf16x2(a[4], a[5]);
        row[3] = pack_bf16x2(a[6], a[7]);
        row[4] = pack_bf16x2(a[8], a[9]);
        row[5] = pack_bf16x2(a[10], a[11]);
        row[6] = pack_bf16x2(a[12], a[13]);
        row[7] = pack_bf16x2(a[14], a[15]);
    }
    __syncthreads();
    // ---- phase B: wave w -> rows (w&1)*16..+15, col-tiles (w>>1)*2..+1 ----
    const int lrow = (w & 1) * 16 + (lane & 15);
    const int lq = lane >> 4;
    const int c0 = (w >> 1) * 2;
    f32x4 acc0 = (f32x4){0.f, 0.f, 0.f, 0.f};
    f32x4 acc1 = (f32x4){0.f, 0.f, 0.f, 0.f};
#pragma unroll
    for (int tt = 0; tt < 4; ++tt) {
        bf16x8 xf = *(const bf16x8*)&x2[lrow][tt * 16 + lq * 4];
        bf16x8 wf0 = *(const bf16x8*)(Wpk2 + (size_t)((c0 * 4 + tt) * 64 + lane) * 8);
        bf16x8 wf1 = *(const bf16x8*)(Wpk2 + (size_t)(((c0 + 1) * 4 + tt) * 64 + lane) * 8);
        acc0 = __builtin_amdgcn_mfma_f32_16x16x32_bf16(wf0, xf, acc0, 0, 0, 0);
        acc1 = __builtin_amdgcn_mfma_f32_16x16x32_bf16(wf1, xf, acc1, 0, 0, 0);
    }
    const int orow_i = nbase + lrow;
    if (orow_i < NN) {
        float s = dinv[orow_i];
        unsigned* orow = H2 + (size_t)orow_i * 16;
        orow[c0 * 4 + lq] = pack_fp8x4(acc0[0] * s, acc0[1] * s, acc0[2] * s, acc0[3] * s);
        orow[(c0 + 1) * 4 + lq] = pack_fp8x4(acc1[0] * s, acc1[1] * s, acc1[2] * s, acc1[3] * s);
    }
}

// ---------------- layer-2 aggregate + log_softmax: 4-lane group per node, uint4/lane ----------------
__global__ void k_agg2_lsm(const int* __restrict__ row_start, const unsigned short* __restrict__ esrc,
                           const unsigned* __restrict__ H2, const float* __restrict__ dinv,
                           const float* __restrict__ b, float* __restrict__ OUT) {
    int wave = (blockIdx.x * blockDim.x + threadIdx.x) >> 6;
    int lane = threadIdx.x & 63;
    int g = lane >> 2, gl = lane & 3;
    int wid = wave * 16 + g;
    if (wid >= NN) return;
    int beg = row_start[wid];
    int n = row_start[wid + 1] - beg;
    const uint4* Hp = (const uint4*)H2;  // row = 4 uint4
    float a[16];
#pragma unroll
    for (int k = 0; k < 16; ++k) a[k] = 0.f;
    int j = 0;
    for (; j + 4 <= n; j += 4) {
        int s0 = esrc[beg + j], s1 = esrc[beg + j + 1];
        int s2 = esrc[beg + j + 2], s3 = esrc[beg + j + 3];
        uint4 v0 = Hp[(size_t)s0 * 4 + gl];
        uint4 v1 = Hp[(size_t)s1 * 4 + gl];
        uint4 v2 = Hp[(size_t)s2 * 4 + gl];
        uint4 v3 = Hp[(size_t)s3 * 4 + gl];
        dec8(v0.x, v0.y, a); dec8(v0.z, v0.w, a + 8);
        dec8(v1.x, v1.y, a); dec8(v1.z, v1.w, a + 8);
        dec8(v2.x, v2.y, a); dec8(v2.z, v2.w, a + 8);
        dec8(v3.x, v3.y, a); dec8(v3.z, v3.w, a + 8);
    }
    for (; j < n; ++j) {
        uint4 v = Hp[(size_t)esrc[beg + j] * 4 + gl];
        dec8(v.x, v.y, a); dec8(v.z, v.w, a + 8);
    }
    {   // self-loop
        uint4 v = Hp[(size_t)wid * 4 + gl];
        dec8(v.x, v.y, a); dec8(v.z, v.w, a + 8);
    }
    float di = dinv[wid];
    float v[16];
    const float4* bp = (const float4*)b;
#pragma unroll
    for (int kq = 0; kq < 4; ++kq) {
        float4 bv = bp[gl * 4 + kq];
        v[kq * 4 + 0] = fmaf(di, a[kq * 4 + 0], bv.x);
        v[kq * 4 + 1] = fmaf(di, a[kq * 4 + 1], bv.y);
        v[kq * 4 + 2] = fmaf(di, a[kq * 4 + 2], bv.z);
        v[kq * 4 + 3] = fmaf(di, a[kq * 4 + 3], bv.w);
    }
    float m = v[0];
#pragma unroll
    for (int k = 1; k < 16; ++k) m = fmaxf(m, v[k]);
    m = fmaxf(m, __shfl_xor(m, 1));
    m = fmaxf(m, __shfl_xor(m, 2));
    float s = 0.f;
#pragma unroll
    for (int k = 0; k < 16; ++k) s += expf(v[k] - m);
    s += __shfl_xor(s, 1);
    s += __shfl_xor(s, 2);
    float ls = m + logf(s);
#pragma unroll
    for (int kq = 0; kq < 4; ++kq) {
        float4 o4;
        o4.x = v[kq * 4 + 0] - ls;
        o4.y = v[kq * 4 + 1] - ls;
        o4.z = v[kq * 4 + 2] - ls;
        o4.w = v[kq * 4 + 3] - ls;
        ((float4*)OUT)[(size_t)wid * 16 + gl * 4 + kq] = o4;
    }
}

extern "C" void kernel_launch(void* const* d_in, const int* in_sizes, int n_in,
                              void* d_out, int out_size, void* d_ws, size_t ws_size,
                              hipStream_t stream) {
    const float* x = (const float*)d_in[0];
    const int* ei = (const int*)d_in[1];  // [2, NE] int32
    const float* W1 = (const float*)d_in[2];
    const float* b1 = (const float*)d_in[3];
    const float* W2 = (const float*)d_in[4];
    const float* b2 = (const float*)d_in[5];
    float* out = (float*)d_out;

    const int* src = ei;
    const int* dst = ei + NE;

    // workspace layout (all segments 16B-aligned)
    int* bbase = (int*)d_ws;                                 // 400 (NB+1 used)
    int* bcur = bbase + 400;                                 // 400
    int* pbh = bcur + 400;                                   // NCH*NBP
    unsigned* eord = (unsigned*)(pbh + NCH * NBP);           // NE
    unsigned short* esrc16 = (unsigned short*)(eord + NE);   // NE
    int* row_start = (int*)(esrc16 + NE);                    // 50016
    float* dinv = (float*)(row_start + 50016);               // NN
    unsigned short* Wpk1 = (unsigned short*)(dinv + NN);     // 2048*8 bf16 (32KB)
    unsigned short* Wpk2 = Wpk1 + 2048 * 8;                  // 1024*8 bf16 (16KB)
    unsigned* H1f8 = (unsigned*)(Wpk2 + 1024 * 8);           // NN*32 u32 (fp8x4, 6.4MB)
    unsigned* H2f8 = H1f8 + (size_t)NN * 32;                 // NN*16 u32 (fp8x4, 3.2MB)

    k_hist<<<NCH + 12, 256, 0, stream>>>(dst, pbh, W1, W2, Wpk1, Wpk2);
    k_bscan<<<1, 512, 0, stream>>>(pbh, bbase, bcur);
    k_scat1<<<NCH, 256, 0, stream>>>(src, dst, bcur, eord);
    k_scat2<<<NB, 256, 0, stream>>>(bbase, eord, esrc16, row_start, dinv);

    // layer 1 (+ fused GEMM2)
    k_gemm1<<<(NN + 63) / 64, 256, 0, stream>>>(x, Wpk1, dinv, H1f8);
    k_agg1g2<<<(NN + 31) / 32, 256, 0, stream>>>(row_start, esrc16, H1f8, dinv, b1, Wpk2, H2f8);
    // layer 2
    k_agg2_lsm<<<(((NN + 15) / 16) * 64 + 255) / 256, 256, 0, stream>>>(row_start, esrc16, H2f8,
                                                                        dinv, b2, out);
}

// Round 16
// 85.923 us; speedup vs baseline: 1.6167x; 1.1603x over previous
//
#include <hip/hip_runtime.h>

#define NN 50000
#define NE 800000
#define NB 391            // dst buckets of 128 nodes (391*128 = 50048)
#define ECAP 3072         // per-bucket edge capacity (mean 2046, +22 sigma; multiple of 4)
#define CHUNK 8192        // edges per scat1 block
#define NCH ((NE + CHUNK - 1) / CHUNK)  // 98 blocks

typedef __attribute__((ext_vector_type(8))) short bf16x8;
typedef __attribute__((ext_vector_type(4))) float f32x4;
typedef __attribute__((ext_vector_type(2))) float f32x2;

__device__ __forceinline__ unsigned pack_bf16x2(float a, float b) {
    unsigned ua = __float_as_uint(a);
    unsigned ub = __float_as_uint(b);
    ua = (ua + 0x7FFFu + ((ua >> 16) & 1u)) >> 16;
    ub = (ub + 0x7FFFu + ((ub >> 16) & 1u)) >> 16;
    return ua | (ub << 16);
}
__device__ __forceinline__ unsigned pack_fp8x4(float a, float b, float c, float d) {
    int w = __builtin_amdgcn_cvt_pk_fp8_f32(a, b, 0, false);
    w = __builtin_amdgcn_cvt_pk_fp8_f32(c, d, w, true);
    return (unsigned)w;
}
__device__ __forceinline__ void dec8(unsigned lo, unsigned hi, float* a) {
    f32x2 p0 = __builtin_amdgcn_cvt_pk_f32_fp8(lo, false);
    f32x2 p1 = __builtin_amdgcn_cvt_pk_f32_fp8(lo, true);
    f32x2 p2 = __builtin_amdgcn_cvt_pk_f32_fp8(hi, false);
    f32x2 p3 = __builtin_amdgcn_cvt_pk_f32_fp8(hi, true);
    a[0] += p0.x; a[1] += p0.y; a[2] += p1.x; a[3] += p1.y;
    a[4] += p2.x; a[5] += p2.y; a[6] += p3.x; a[7] += p3.y;
}

// ---------------- prep: W pack (blocks 0-11) + bcnt clear + sentinel rows (block 12) ----------------
__global__ void k_prep(const float* __restrict__ W1, const float* __restrict__ W2,
                       unsigned short* __restrict__ Wpk1, unsigned short* __restrict__ Wpk2,
                       int* __restrict__ bcnt, unsigned* __restrict__ H1, unsigned* __restrict__ H2) {
    const int t = threadIdx.x;
    if (blockIdx.x == 12) {
        for (int j = t; j < NB; j += 256) bcnt[j] = 0;       // ALL of bcnt (NB=391 > 256!)
        if (t < 32) H1[(size_t)NN * 32 + t] = 0;             // zero sentinel row of H1
        else if (t < 48) H2[(size_t)NN * 16 + (t - 32)] = 0; // zero sentinel row of H2
        return;
    }
    int gid = blockIdx.x * 256 + t;
    const float* W;
    unsigned short* Wpk;
    int idx, M;
    if (gid < 2048) { W = W1; Wpk = Wpk1; idx = gid; M = 128; }
    else if (gid < 3072) { W = W2; Wpk = Wpk2; idx = gid - 2048; M = 64; }
    else return;
    int l = idx & 63;
    int tt = (idx >> 6) & 3;
    int ct = idx >> 8;
    int col = ct * 16 + (l & 15);
    int k0 = tt * 32 + (l >> 4) * 8;
    unsigned* o = (unsigned*)(Wpk + (size_t)idx * 8);
#pragma unroll
    for (int j = 0; j < 8; j += 2)
        o[j >> 1] = pack_bf16x2(W[(size_t)(k0 + j) * M + col], W[(size_t)(k0 + j + 1) * M + col]);
}

// ---------------- pass 1: bucket-bin edges into fixed-capacity regions ----------------
// packed edge: [31:16]=dst, [15:0]=src ; bucket = pk>>23
__global__ void k_scat1(const int* __restrict__ src, const int* __restrict__ dst,
                        int* __restrict__ bcnt, unsigned* __restrict__ eord) {
    __shared__ int hist[NB];
    __shared__ int gbase[NB];
    const int t = threadIdx.x;
    const int e0 = blockIdx.x * CHUNK;
    for (int j = t; j < NB; j += 256) hist[j] = 0;
    __syncthreads();
    unsigned pk[32];
#pragma unroll
    for (int i = 0; i < 32; ++i) {
        int e = e0 + t + i * 256;
        pk[i] = 0xFFFFFFFFu;
        if (e < NE) {
            unsigned s = (unsigned)src[e];
            unsigned d = (unsigned)dst[e];
            pk[i] = (d << 16) | s;
            atomicAdd(&hist[d >> 7], 1);
        }
    }
    __syncthreads();
    for (int j = t; j < NB; j += 256) {
        int c = hist[j];
        gbase[j] = c ? atomicAdd(&bcnt[j], c) : 0;
        hist[j] = 0;  // reuse as within-block cursor
    }
    __syncthreads();
#pragma unroll
    for (int i = 0; i < 32; ++i) {
        if (pk[i] != 0xFFFFFFFFu) {
            int bk = pk[i] >> 23;
            int pos = bk * ECAP + gbase[bk] + atomicAdd(&hist[bk], 1);
            eord[pos] = pk[i];
        }
    }
}

// ---------------- pass 2: within-bucket sort -> padded esrc16 + rs2 + dinv ----------------
// Each node's range padded to a multiple of 4 with sentinel NN (zero row).
__global__ void k_scat2(const int* __restrict__ bcnt, const unsigned* __restrict__ eord,
                        unsigned short* __restrict__ esrc16, uint2* __restrict__ rs2,
                        float* __restrict__ dinv) {
    __shared__ int cnt[128];
    __shared__ int pre[128];
    __shared__ int cur[128];
    const int b = blockIdx.x, t = threadIdx.x, d0 = b << 7;
    const int base = b * ECAP;
    const int nE = bcnt[b];
    if (t < 128) cnt[t] = 0;
    __syncthreads();
    unsigned pk[12];
#pragma unroll
    for (int it = 0; it < 12; ++it) {
        int i = t + it * 256;
        if (i < nE) {
            pk[it] = eord[base + i];
            atomicAdd(&cnt[(pk[it] >> 16) & 127], 1);
        }
    }
    __syncthreads();
    int v = (t < 128) ? cnt[t] : 0;
    int pc = (v + 3) & ~3;  // pad to multiple of 4
    if (t < 128) pre[t] = pc;
    __syncthreads();
    for (int o = 1; o < 128; o <<= 1) {
        int a = (t < 128 && t >= o) ? pre[t - o] : 0;
        __syncthreads();
        if (t < 128) pre[t] += a;
        __syncthreads();
    }
    if (t < 128) {
        int st = base + pre[t] - pc;
        int d = d0 + t;
        if (d < NN) {
            rs2[d] = make_uint2((unsigned)st, (unsigned)pc);
            dinv[d] = rsqrtf((float)(v + 1));  // +1 self-loop
        }
        cur[t] = st;
        for (int k = v; k < pc; ++k) esrc16[st + k] = (unsigned short)NN;  // sentinel pads
    }
    __syncthreads();
#pragma unroll
    for (int it = 0; it < 12; ++it) {
        int i = t + it * 256;
        if (i < nE) {
            int pos = atomicAdd(&cur[(pk[it] >> 16) & 127], 1);
            esrc16[pos] = (unsigned short)(pk[it] & 0xFFFFu);
        }
    }
}

// ---------------- MFMA GEMM1: H1f8[N+1,32 u32] = fp8(dinv * (X @ W1)), reads f32 X ----------------
__global__ __launch_bounds__(256) void k_gemm1(const float* __restrict__ X,
                                               const unsigned short* __restrict__ Wpk,
                                               const float* __restrict__ dinv,
                                               unsigned* __restrict__ H1) {
    const int t = threadIdx.x;
    const int w = t >> 6, l = t & 63;
    const int row = blockIdx.x * 64 + w * 16 + (l & 15);
    const int rc = row < NN ? row : NN - 1;
    const int lq = l >> 4;
    f32x4 acc[8];
#pragma unroll
    for (int c = 0; c < 8; ++c) acc[c] = (f32x4){0.f, 0.f, 0.f, 0.f};
#pragma unroll
    for (int tt = 0; tt < 4; ++tt) {
        const float4* xp = (const float4*)(X + (size_t)rc * 128 + tt * 32 + lq * 8);
        float4 xa = xp[0], xb = xp[1];
        bf16x8 xf;
        unsigned* xu = (unsigned*)&xf;
        xu[0] = pack_bf16x2(xa.x, xa.y);
        xu[1] = pack_bf16x2(xa.z, xa.w);
        xu[2] = pack_bf16x2(xb.x, xb.y);
        xu[3] = pack_bf16x2(xb.z, xb.w);
#pragma unroll
        for (int c = 0; c < 8; ++c) {
            bf16x8 wf = *(const bf16x8*)(Wpk + (size_t)((c * 4 + tt) * 64 + l) * 8);
            acc[c] = __builtin_amdgcn_mfma_f32_16x16x32_bf16(wf, xf, acc[c], 0, 0, 0);
        }
    }
    if (row < NN) {
        float s = dinv[row];
        unsigned* orow = H1 + (size_t)row * 32;
#pragma unroll
        for (int c = 0; c < 8; ++c)
            orow[c * 4 + lq] = pack_fp8x4(acc[c][0] * s, acc[c][1] * s, acc[c][2] * s, acc[c][3] * s);
    }
}

// ---------------- FUSED layer-1 aggregate + GEMM2 ----------------
__global__ __launch_bounds__(256) void k_agg1g2(const uint2* __restrict__ rs2,
                                                const unsigned short* __restrict__ esrc,
                                                const unsigned* __restrict__ H1,
                                                const float* __restrict__ dinv,
                                                const float* __restrict__ b1,
                                                const unsigned short* __restrict__ Wpk2,
                                                unsigned* __restrict__ H2) {
    __shared__ unsigned x2[32][68];  // 32 nodes x 128 bf16, stride 68 u32 -> 2-way-free banks
    const int t = threadIdx.x;
    const int w = t >> 6, lane = t & 63;
    const int g = lane >> 3, gl = lane & 7;
    const int nbase = blockIdx.x * 32;
    const int wid = nbase + w * 8 + g;
    float a[16];
#pragma unroll
    for (int k = 0; k < 16; ++k) a[k] = 0.f;
    if (wid < NN) {
        uint2 r = rs2[wid];
        const unsigned short* ep = esrc + r.x;
        int n4 = (int)r.y;
        const uint4* Hp = (const uint4*)H1;  // row = 8 uint4
        for (int j = 0; j < n4; j += 4) {
            unsigned long long i4 = *(const unsigned long long*)(ep + j);
            int s0 = (int)(i4 & 0xFFFF), s1 = (int)((i4 >> 16) & 0xFFFF);
            int s2 = (int)((i4 >> 32) & 0xFFFF), s3 = (int)(i4 >> 48);
            uint4 v0 = Hp[(size_t)s0 * 8 + gl];
            uint4 v1 = Hp[(size_t)s1 * 8 + gl];
            uint4 v2 = Hp[(size_t)s2 * 8 + gl];
            uint4 v3 = Hp[(size_t)s3 * 8 + gl];
            dec8(v0.x, v0.y, a); dec8(v0.z, v0.w, a + 8);
            dec8(v1.x, v1.y, a); dec8(v1.z, v1.w, a + 8);
            dec8(v2.x, v2.y, a); dec8(v2.z, v2.w, a + 8);
            dec8(v3.x, v3.y, a); dec8(v3.z, v3.w, a + 8);
        }
        {   // self-loop
            uint4 v = Hp[(size_t)wid * 8 + gl];
            dec8(v.x, v.y, a); dec8(v.z, v.w, a + 8);
        }
        float di = dinv[wid];
        const float4* bp = (const float4*)b1;
#pragma unroll
        for (int kq = 0; kq < 4; ++kq) {
            float4 bv = bp[gl * 4 + kq];
            a[kq * 4 + 0] = fmaxf(fmaf(di, a[kq * 4 + 0], bv.x), 0.f);
            a[kq * 4 + 1] = fmaxf(fmaf(di, a[kq * 4 + 1], bv.y), 0.f);
            a[kq * 4 + 2] = fmaxf(fmaf(di, a[kq * 4 + 2], bv.z), 0.f);
            a[kq * 4 + 3] = fmaxf(fmaf(di, a[kq * 4 + 3], bv.w), 0.f);
        }
    }
    {   // stage X2 row (bf16) to LDS
        const int nl = w * 8 + g;
        unsigned* row = &x2[nl][gl * 8];
        row[0] = pack_bf16x2(a[0], a[1]);
        row[1] = pack_bf16x2(a[2], a[3]);
        row[2] = pack_bf16x2(a[4], a[5]);
        row[3] = pack_bf16x2(a[6], a[7]);
        row[4] = pack_bf16x2(a[8], a[9]);
        row[5] = pack_bf16x2(a[10], a[11]);
        row[6] = pack_bf16x2(a[12], a[13]);
        row[7] = pack_bf16x2(a[14], a[15]);
    }
    __syncthreads();
    // ---- phase B: wave w -> rows (w&1)*16..+15, col-tiles (w>>1)*2..+1 ----
    const int lrow = (w & 1) * 16 + (lane & 15);
    const int lq = lane >> 4;
    const int c0 = (w >> 1) * 2;
    f32x4 acc0 = (f32x4){0.f, 0.f, 0.f, 0.f};
    f32x4 acc1 = (f32x4){0.f, 0.f, 0.f, 0.f};
#pragma unroll
    for (int tt = 0; tt < 4; ++tt) {
        bf16x8 xf = *(const bf16x8*)&x2[lrow][tt * 16 + lq * 4];
        bf16x8 wf0 = *(const bf16x8*)(Wpk2 + (size_t)((c0 * 4 + tt) * 64 + lane) * 8);
        bf16x8 wf1 = *(const bf16x8*)(Wpk2 + (size_t)(((c0 + 1) * 4 + tt) * 64 + lane) * 8);
        acc0 = __builtin_amdgcn_mfma_f32_16x16x32_bf16(wf0, xf, acc0, 0, 0, 0);
        acc1 = __builtin_amdgcn_mfma_f32_16x16x32_bf16(wf1, xf, acc1, 0, 0, 0);
    }
    const int orow_i = nbase + lrow;
    if (orow_i < NN) {
        float s = dinv[orow_i];
        unsigned* orow = H2 + (size_t)orow_i * 16;
        orow[c0 * 4 + lq] = pack_fp8x4(acc0[0] * s, acc0[1] * s, acc0[2] * s, acc0[3] * s);
        orow[(c0 + 1) * 4 + lq] = pack_fp8x4(acc1[0] * s, acc1[1] * s, acc1[2] * s, acc1[3] * s);
    }
}

// ---------------- layer-2 aggregate + log_softmax: 4-lane group per node, uint4/lane ----------------
__global__ void k_agg2_lsm(const uint2* __restrict__ rs2, const unsigned short* __restrict__ esrc,
                           const unsigned* __restrict__ H2, const float* __restrict__ dinv,
                           const float* __restrict__ b, float* __restrict__ OUT) {
    int wave = (blockIdx.x * blockDim.x + threadIdx.x) >> 6;
    int lane = threadIdx.x & 63;
    int g = lane >> 2, gl = lane & 3;
    int wid = wave * 16 + g;
    if (wid >= NN) return;
    uint2 r = rs2[wid];
    const unsigned short* ep = esrc + r.x;
    int n4 = (int)r.y;
    const uint4* Hp = (const uint4*)H2;  // row = 4 uint4
    float a[16];
#pragma unroll
    for (int k = 0; k < 16; ++k) a[k] = 0.f;
    for (int j = 0; j < n4; j += 4) {
        unsigned long long i4 = *(const unsigned long long*)(ep + j);
        int s0 = (int)(i4 & 0xFFFF), s1 = (int)((i4 >> 16) & 0xFFFF);
        int s2 = (int)((i4 >> 32) & 0xFFFF), s3 = (int)(i4 >> 48);
        uint4 v0 = Hp[(size_t)s0 * 4 + gl];
        uint4 v1 = Hp[(size_t)s1 * 4 + gl];
        uint4 v2 = Hp[(size_t)s2 * 4 + gl];
        uint4 v3 = Hp[(size_t)s3 * 4 + gl];
        dec8(v0.x, v0.y, a); dec8(v0.z, v0.w, a + 8);
        dec8(v1.x, v1.y, a); dec8(v1.z, v1.w, a + 8);
        dec8(v2.x, v2.y, a); dec8(v2.z, v2.w, a + 8);
        dec8(v3.x, v3.y, a); dec8(v3.z, v3.w, a + 8);
    }
    {   // self-loop
        uint4 v = Hp[(size_t)wid * 4 + gl];
        dec8(v.x, v.y, a); dec8(v.z, v.w, a + 8);
    }
    float di = dinv[wid];
    float v[16];
    const float4* bp = (const float4*)b;
#pragma unroll
    for (int kq = 0; kq < 4; ++kq) {
        float4 bv = bp[gl * 4 + kq];
        v[kq * 4 + 0] = fmaf(di, a[kq * 4 + 0], bv.x);
        v[kq * 4 + 1] = fmaf(di, a[kq * 4 + 1], bv.y);
        v[kq * 4 + 2] = fmaf(di, a[kq * 4 + 2], bv.z);
        v[kq * 4 + 3] = fmaf(di, a[kq * 4 + 3], bv.w);
    }
    float m = v[0];
#pragma unroll
    for (int k = 1; k < 16; ++k) m = fmaxf(m, v[k]);
    m = fmaxf(m, __shfl_xor(m, 1));
    m = fmaxf(m, __shfl_xor(m, 2));
    float s = 0.f;
#pragma unroll
    for (int k = 0; k < 16; ++k) s += expf(v[k] - m);
    s += __shfl_xor(s, 1);
    s += __shfl_xor(s, 2);
    float ls = m + logf(s);
#pragma unroll
    for (int kq = 0; kq < 4; ++kq) {
        float4 o4;
        o4.x = v[kq * 4 + 0] - ls;
        o4.y = v[kq * 4 + 1] - ls;
        o4.z = v[kq * 4 + 2] - ls;
        o4.w = v[kq * 4 + 3] - ls;
        ((float4*)OUT)[(size_t)wid * 16 + gl * 4 + kq] = o4;
    }
}

extern "C" void kernel_launch(void* const* d_in, const int* in_sizes, int n_in,
                              void* d_out, int out_size, void* d_ws, size_t ws_size,
                              hipStream_t stream) {
    const float* x = (const float*)d_in[0];
    const int* ei = (const int*)d_in[1];  // [2, NE] int32
    const float* W1 = (const float*)d_in[2];
    const float* b1 = (const float*)d_in[3];
    const float* W2 = (const float*)d_in[4];
    const float* b2 = (const float*)d_in[5];
    float* out = (float*)d_out;

    const int* src = ei;
    const int* dst = ei + NE;

    // workspace layout (all segments 16B-aligned)
    int* bcnt = (int*)d_ws;                                  // 400 (NB used)
    uint2* rs2 = (uint2*)(bcnt + 400);                       // NN uint2
    float* dinv = (float*)(rs2 + NN);                        // NN
    unsigned short* Wpk1 = (unsigned short*)(dinv + NN);     // 2048*8 bf16 (32KB)
    unsigned short* Wpk2 = Wpk1 + 2048 * 8;                  // 1024*8 bf16 (16KB)
    unsigned* eord = (unsigned*)(Wpk2 + 1024 * 8);           // NB*ECAP u32 (4.8MB)
    unsigned short* esrc16 = (unsigned short*)(eord + (size_t)NB * ECAP);  // NB*ECAP u16 (2.4MB)
    unsigned* H1f8 = (unsigned*)(esrc16 + (size_t)NB * ECAP);  // (NN+1)*32 u32 (fp8, +sentinel)
    unsigned* H2f8 = H1f8 + (size_t)(NN + 1) * 32;           // (NN+1)*16 u32 (fp8, +sentinel)

    k_prep<<<13, 256, 0, stream>>>(W1, W2, Wpk1, Wpk2, bcnt, H1f8, H2f8);
    k_scat1<<<NCH, 256, 0, stream>>>(src, dst, bcnt, eord);
    k_scat2<<<NB, 256, 0, stream>>>(bcnt, eord, esrc16, rs2, dinv);

    // layer 1 (+ fused GEMM2)
    k_gemm1<<<(NN + 63) / 64, 256, 0, stream>>>(x, Wpk1, dinv, H1f8);
    k_agg1g2<<<(NN + 31) / 32, 256, 0, stream>>>(rs2, esrc16, H1f8, dinv, b1, Wpk2, H2f8);
    // layer 2
    k_agg2_lsm<<<(((NN + 15) / 16) * 64 + 255) / 256, 256, 0, stream>>>(rs2, esrc16, H2f8,
                                                                        dinv, b2, out);
}

// Round 17
// 82.130 us; speedup vs baseline: 1.6914x; 1.0462x over previous
//
#include <hip/hip_runtime.h>

#define NN 50000
#define NE 800000
#define NB 391            // dst buckets of 128 nodes (391*128 = 50048)
#define ECAP 3072         // per-bucket padded esrc16 capacity (max ~2300+pads)
#define SCAP 80           // per-(chunk,bucket) eord slot capacity (mean 21, +13 sigma)
#define CHUNK 8192        // edges per scat1 block
#define NCH ((NE + CHUNK - 1) / CHUNK)  // 98 chunks

typedef __attribute__((ext_vector_type(8))) short bf16x8;
typedef __attribute__((ext_vector_type(4))) float f32x4;
typedef __attribute__((ext_vector_type(2))) float f32x2;

__device__ __forceinline__ unsigned pack_bf16x2(float a, float b) {
    unsigned ua = __float_as_uint(a);
    unsigned ub = __float_as_uint(b);
    ua = (ua + 0x7FFFu + ((ua >> 16) & 1u)) >> 16;
    ub = (ub + 0x7FFFu + ((ub >> 16) & 1u)) >> 16;
    return ua | (ub << 16);
}
__device__ __forceinline__ unsigned pack_fp8x4(float a, float b, float c, float d) {
    int w = __builtin_amdgcn_cvt_pk_fp8_f32(a, b, 0, false);
    w = __builtin_amdgcn_cvt_pk_fp8_f32(c, d, w, true);
    return (unsigned)w;
}
__device__ __forceinline__ void dec8(unsigned lo, unsigned hi, float* a) {
    f32x2 p0 = __builtin_amdgcn_cvt_pk_f32_fp8(lo, false);
    f32x2 p1 = __builtin_amdgcn_cvt_pk_f32_fp8(lo, true);
    f32x2 p2 = __builtin_amdgcn_cvt_pk_f32_fp8(hi, false);
    f32x2 p3 = __builtin_amdgcn_cvt_pk_f32_fp8(hi, true);
    a[0] += p0.x; a[1] += p0.y; a[2] += p1.x; a[3] += p1.y;
    a[4] += p2.x; a[5] += p2.y; a[6] += p3.x; a[7] += p3.y;
}

// ---------------- pass 1 + prep: bucket-bin edges into fixed (chunk,bucket) slots ----------------
// blocks 0..NCH-1: binning. blocks NCH..NCH+11: W pack. block NCH+12: sentinel rows.
// packed edge: [31:16]=dst, [15:0]=src ; bucket = pk>>23
__global__ void k_scat1(const int* __restrict__ src, const int* __restrict__ dst,
                        int* __restrict__ pcnt, unsigned* __restrict__ eord,
                        const float* __restrict__ W1, const float* __restrict__ W2,
                        unsigned short* __restrict__ Wpk1, unsigned short* __restrict__ Wpk2,
                        unsigned* __restrict__ H1, unsigned* __restrict__ H2) {
    const int t = threadIdx.x;
    if (blockIdx.x >= NCH) {
        if (blockIdx.x == NCH + 12) {  // zero sentinel rows (node NN)
            if (t < 32) H1[(size_t)NN * 32 + t] = 0;
            else if (t < 48) H2[(size_t)NN * 16 + (t - 32)] = 0;
            return;
        }
        int gid = (blockIdx.x - NCH) * 256 + t;  // W-pack
        const float* W;
        unsigned short* Wpk;
        int idx, M;
        if (gid < 2048) { W = W1; Wpk = Wpk1; idx = gid; M = 128; }
        else if (gid < 3072) { W = W2; Wpk = Wpk2; idx = gid - 2048; M = 64; }
        else return;
        int l = idx & 63;
        int tt = (idx >> 6) & 3;
        int ct = idx >> 8;
        int col = ct * 16 + (l & 15);
        int k0 = tt * 32 + (l >> 4) * 8;
        unsigned* o = (unsigned*)(Wpk + (size_t)idx * 8);
#pragma unroll
        for (int j = 0; j < 8; j += 2)
            o[j >> 1] = pack_bf16x2(W[(size_t)(k0 + j) * M + col], W[(size_t)(k0 + j + 1) * M + col]);
        return;
    }
    __shared__ int hist[NB];
    const int e0 = blockIdx.x * CHUNK;
    for (int j = t; j < NB; j += 256) hist[j] = 0;
    __syncthreads();
    unsigned pk[32];
#pragma unroll
    for (int i = 0; i < 32; ++i) {
        int e = e0 + t + i * 256;
        pk[i] = 0xFFFFFFFFu;
        if (e < NE) {
            unsigned s = (unsigned)src[e];
            unsigned d = (unsigned)dst[e];
            pk[i] = (d << 16) | s;
            atomicAdd(&hist[d >> 7], 1);
        }
    }
    __syncthreads();
    for (int j = t; j < NB; j += 256) {
        pcnt[(size_t)j * NCH + blockIdx.x] = hist[j];
        hist[j] = 0;  // reuse as within-block cursor
    }
    __syncthreads();
#pragma unroll
    for (int i = 0; i < 32; ++i) {
        if (pk[i] != 0xFFFFFFFFu) {
            int bk = pk[i] >> 23;
            int pos = ((int)((size_t)0) + bk * NCH + blockIdx.x) * SCAP + atomicAdd(&hist[bk], 1);
            eord[pos] = pk[i];
        }
    }
}

// ---------------- pass 2 + GEMM1: within-bucket sort -> esrc16/rs2/dinv, then MFMA for 128 rows ----------------
__global__ __launch_bounds__(256) void k_scat2g1(const int* __restrict__ pcnt,
                                                 const unsigned* __restrict__ eord,
                                                 unsigned short* __restrict__ esrc16,
                                                 uint2* __restrict__ rs2, float* __restrict__ dinv,
                                                 const float* __restrict__ X,
                                                 const unsigned short* __restrict__ Wpk,
                                                 unsigned* __restrict__ H1) {
    __shared__ int sp[NCH + 1];   // segment exclusive prefix
    __shared__ int tmp[128];
    __shared__ int cnt[128];
    __shared__ int pre[128];
    __shared__ int cur[128];
    __shared__ float sdv[128];
    const int b = blockIdx.x, t = threadIdx.x, d0 = b << 7;
    const int base = b * ECAP;
    // segment counts -> prefix (98 entries via 128-thread scan)
    int c = 0;
    if (t < NCH) c = pcnt[(size_t)b * NCH + t];
    if (t < 128) tmp[t] = (t < NCH) ? c : 0;
    if (t < 128) cnt[t] = 0;
    __syncthreads();
    for (int o = 1; o < 128; o <<= 1) {
        int a = (t < 128 && t >= o) ? tmp[t - o] : 0;
        __syncthreads();
        if (t < 128) tmp[t] += a;
        __syncthreads();
    }
    if (t < NCH) sp[t + 1] = tmp[t];
    if (t == 0) sp[0] = 0;
    __syncthreads();
    const int nE = sp[NCH];
    // gather edges (binary search segment), histogram by dst&127
    unsigned pk[12];
#pragma unroll
    for (int it = 0; it < 12; ++it) {
        int i = t + it * 256;
        if (i < nE) {
            int lo = 0, hi = NCH - 1;
            while (lo < hi) {
                int mid = (lo + hi + 1) >> 1;
                if (sp[mid] <= i) lo = mid; else hi = mid - 1;
            }
            pk[it] = eord[((size_t)b * NCH + lo) * SCAP + (i - sp[lo])];
            atomicAdd(&cnt[(pk[it] >> 16) & 127], 1);
        }
    }
    __syncthreads();
    int v = (t < 128) ? cnt[t] : 0;
    int pc = (v + 3) & ~3;  // pad to multiple of 4
    if (t < 128) pre[t] = pc;
    __syncthreads();
    for (int o = 1; o < 128; o <<= 1) {
        int a = (t < 128 && t >= o) ? pre[t - o] : 0;
        __syncthreads();
        if (t < 128) pre[t] += a;
        __syncthreads();
    }
    if (t < 128) {
        int st = base + pre[t] - pc;
        int d = d0 + t;
        float dv = rsqrtf((float)(v + 1));  // +1 self-loop
        sdv[t] = dv;
        if (d < NN) {
            rs2[d] = make_uint2((unsigned)st, (unsigned)pc);
            dinv[d] = dv;
        }
        cur[t] = st;
        for (int k = v; k < pc; ++k) esrc16[st + k] = (unsigned short)NN;  // sentinel pads
    }
    __syncthreads();
#pragma unroll
    for (int it = 0; it < 12; ++it) {
        int i = t + it * 256;
        if (i < nE) {
            int pos = atomicAdd(&cur[(pk[it] >> 16) & 127], 1);
            esrc16[pos] = (unsigned short)(pk[it] & 0xFFFFu);
        }
    }
    __syncthreads();
    // ---- GEMM1 for this bucket's 128 rows: 2 passes of 64 (4 waves x 16 rows) ----
    const int w = t >> 6, l = t & 63;
    const int lq = l >> 4;
    for (int pass = 0; pass < 2; ++pass) {
        const int lrow = pass * 64 + w * 16 + (l & 15);
        const int row = d0 + lrow;
        const int rc = row < NN ? row : NN - 1;
        f32x4 acc[8];
#pragma unroll
        for (int cc = 0; cc < 8; ++cc) acc[cc] = (f32x4){0.f, 0.f, 0.f, 0.f};
#pragma unroll
        for (int tt = 0; tt < 4; ++tt) {
            const float4* xp = (const float4*)(X + (size_t)rc * 128 + tt * 32 + lq * 8);
            float4 xa = xp[0], xb = xp[1];
            bf16x8 xf;
            unsigned* xu = (unsigned*)&xf;
            xu[0] = pack_bf16x2(xa.x, xa.y);
            xu[1] = pack_bf16x2(xa.z, xa.w);
            xu[2] = pack_bf16x2(xb.x, xb.y);
            xu[3] = pack_bf16x2(xb.z, xb.w);
#pragma unroll
            for (int cc = 0; cc < 8; ++cc) {
                bf16x8 wf = *(const bf16x8*)(Wpk + (size_t)((cc * 4 + tt) * 64 + l) * 8);
                acc[cc] = __builtin_amdgcn_mfma_f32_16x16x32_bf16(wf, xf, acc[cc], 0, 0, 0);
            }
        }
        if (row < NN) {
            float s = sdv[lrow];
            unsigned* orow = H1 + (size_t)row * 32;
#pragma unroll
            for (int cc = 0; cc < 8; ++cc)
                orow[cc * 4 + lq] = pack_fp8x4(acc[cc][0] * s, acc[cc][1] * s,
                                               acc[cc][2] * s, acc[cc][3] * s);
        }
    }
}

// ---------------- FUSED layer-1 aggregate + GEMM2 ----------------
__global__ __launch_bounds__(256) void k_agg1g2(const uint2* __restrict__ rs2,
                                                const unsigned short* __restrict__ esrc,
                                                const unsigned* __restrict__ H1,
                                                const float* __restrict__ dinv,
                                                const float* __restrict__ b1,
                                                const unsigned short* __restrict__ Wpk2,
                                                unsigned* __restrict__ H2) {
    __shared__ unsigned x2[32][68];  // 32 nodes x 128 bf16, stride 68 u32 -> 2-way-free banks
    const int t = threadIdx.x;
    const int w = t >> 6, lane = t & 63;
    const int g = lane >> 3, gl = lane & 7;
    const int nbase = blockIdx.x * 32;
    const int wid = nbase + w * 8 + g;
    float a[16];
#pragma unroll
    for (int k = 0; k < 16; ++k) a[k] = 0.f;
    if (wid < NN) {
        uint2 r = rs2[wid];
        const unsigned short* ep = esrc + r.x;
        int n4 = (int)r.y;
        const uint4* Hp = (const uint4*)H1;  // row = 8 uint4
        for (int j = 0; j < n4; j += 4) {
            unsigned long long i4 = *(const unsigned long long*)(ep + j);
            int s0 = (int)(i4 & 0xFFFF), s1 = (int)((i4 >> 16) & 0xFFFF);
            int s2 = (int)((i4 >> 32) & 0xFFFF), s3 = (int)(i4 >> 48);
            uint4 v0 = Hp[(size_t)s0 * 8 + gl];
            uint4 v1 = Hp[(size_t)s1 * 8 + gl];
            uint4 v2 = Hp[(size_t)s2 * 8 + gl];
            uint4 v3 = Hp[(size_t)s3 * 8 + gl];
            dec8(v0.x, v0.y, a); dec8(v0.z, v0.w, a + 8);
            dec8(v1.x, v1.y, a); dec8(v1.z, v1.w, a + 8);
            dec8(v2.x, v2.y, a); dec8(v2.z, v2.w, a + 8);
            dec8(v3.x, v3.y, a); dec8(v3.z, v3.w, a + 8);
        }
        {   // self-loop
            uint4 v = Hp[(size_t)wid * 8 + gl];
            dec8(v.x, v.y, a); dec8(v.z, v.w, a + 8);
        }
        float di = dinv[wid];
        const float4* bp = (const float4*)b1;
#pragma unroll
        for (int kq = 0; kq < 4; ++kq) {
            float4 bv = bp[gl * 4 + kq];
            a[kq * 4 + 0] = fmaxf(fmaf(di, a[kq * 4 + 0], bv.x), 0.f);
            a[kq * 4 + 1] = fmaxf(fmaf(di, a[kq * 4 + 1], bv.y), 0.f);
            a[kq * 4 + 2] = fmaxf(fmaf(di, a[kq * 4 + 2], bv.z), 0.f);
            a[kq * 4 + 3] = fmaxf(fmaf(di, a[kq * 4 + 3], bv.w), 0.f);
        }
    }
    {   // stage X2 row (bf16) to LDS
        const int nl = w * 8 + g;
        unsigned* row = &x2[nl][gl * 8];
        row[0] = pack_bf16x2(a[0], a[1]);
        row[1] = pack_bf16x2(a[2], a[3]);
        row[2] = pack_bf16x2(a[4], a[5]);
        row[3] = pack_bf16x2(a[6], a[7]);
        row[4] = pack_bf16x2(a[8], a[9]);
        row[5] = pack_bf16x2(a[10], a[11]);
        row[6] = pack_bf16x2(a[12], a[13]);
        row[7] = pack_bf16x2(a[14], a[15]);
    }
    __syncthreads();
    // ---- phase B: wave w -> rows (w&1)*16..+15, col-tiles (w>>1)*2..+1 ----
    const int lrow = (w & 1) * 16 + (lane & 15);
    const int lq = lane >> 4;
    const int c0 = (w >> 1) * 2;
    f32x4 acc0 = (f32x4){0.f, 0.f, 0.f, 0.f};
    f32x4 acc1 = (f32x4){0.f, 0.f, 0.f, 0.f};
#pragma unroll
    for (int tt = 0; tt < 4; ++tt) {
        bf16x8 xf = *(const bf16x8*)&x2[lrow][tt * 16 + lq * 4];
        bf16x8 wf0 = *(const bf16x8*)(Wpk2 + (size_t)((c0 * 4 + tt) * 64 + lane) * 8);
        bf16x8 wf1 = *(const bf16x8*)(Wpk2 + (size_t)(((c0 + 1) * 4 + tt) * 64 + lane) * 8);
        acc0 = __builtin_amdgcn_mfma_f32_16x16x32_bf16(wf0, xf, acc0, 0, 0, 0);
        acc1 = __builtin_amdgcn_mfma_f32_16x16x32_bf16(wf1, xf, acc1, 0, 0, 0);
    }
    const int orow_i = nbase + lrow;
    if (orow_i < NN) {
        float s = dinv[orow_i];
        unsigned* orow = H2 + (size_t)orow_i * 16;
        orow[c0 * 4 + lq] = pack_fp8x4(acc0[0] * s, acc0[1] * s, acc0[2] * s, acc0[3] * s);
        orow[(c0 + 1) * 4 + lq] = pack_fp8x4(acc1[0] * s, acc1[1] * s, acc1[2] * s, acc1[3] * s);
    }
}

// ---------------- layer-2 aggregate + log_softmax: 4-lane group per node, uint4/lane ----------------
__global__ void k_agg2_lsm(const uint2* __restrict__ rs2, const unsigned short* __restrict__ esrc,
                           const unsigned* __restrict__ H2, const float* __restrict__ dinv,
                           const float* __restrict__ b, float* __restrict__ OUT) {
    int wave = (blockIdx.x * blockDim.x + threadIdx.x) >> 6;
    int lane = threadIdx.x & 63;
    int g = lane >> 2, gl = lane & 3;
    int wid = wave * 16 + g;
    if (wid >= NN) return;
    uint2 r = rs2[wid];
    const unsigned short* ep = esrc + r.x;
    int n4 = (int)r.y;
    const uint4* Hp = (const uint4*)H2;  // row = 4 uint4
    float a[16];
#pragma unroll
    for (int k = 0; k < 16; ++k) a[k] = 0.f;
    for (int j = 0; j < n4; j += 4) {
        unsigned long long i4 = *(const unsigned long long*)(ep + j);
        int s0 = (int)(i4 & 0xFFFF), s1 = (int)((i4 >> 16) & 0xFFFF);
        int s2 = (int)((i4 >> 32) & 0xFFFF), s3 = (int)(i4 >> 48);
        uint4 v0 = Hp[(size_t)s0 * 4 + gl];
        uint4 v1 = Hp[(size_t)s1 * 4 + gl];
        uint4 v2 = Hp[(size_t)s2 * 4 + gl];
        uint4 v3 = Hp[(size_t)s3 * 4 + gl];
        dec8(v0.x, v0.y, a); dec8(v0.z, v0.w, a + 8);
        dec8(v1.x, v1.y, a); dec8(v1.z, v1.w, a + 8);
        dec8(v2.x, v2.y, a); dec8(v2.z, v2.w, a + 8);
        dec8(v3.x, v3.y, a); dec8(v3.z, v3.w, a + 8);
    }
    {   // self-loop
        uint4 v = Hp[(size_t)wid * 4 + gl];
        dec8(v.x, v.y, a); dec8(v.z, v.w, a + 8);
    }
    float di = dinv[wid];
    float v[16];
    const float4* bp = (const float4*)b;
#pragma unroll
    for (int kq = 0; kq < 4; ++kq) {
        float4 bv = bp[gl * 4 + kq];
        v[kq * 4 + 0] = fmaf(di, a[kq * 4 + 0], bv.x);
        v[kq * 4 + 1] = fmaf(di, a[kq * 4 + 1], bv.y);
        v[kq * 4 + 2] = fmaf(di, a[kq * 4 + 2], bv.z);
        v[kq * 4 + 3] = fmaf(di, a[kq * 4 + 3], bv.w);
    }
    float m = v[0];
#pragma unroll
    for (int k = 1; k < 16; ++k) m = fmaxf(m, v[k]);
    m = fmaxf(m, __shfl_xor(m, 1));
    m = fmaxf(m, __shfl_xor(m, 2));
    float s = 0.f;
#pragma unroll
    for (int k = 0; k < 16; ++k) s += expf(v[k] - m);
    s += __shfl_xor(s, 1);
    s += __shfl_xor(s, 2);
    float ls = m + logf(s);
#pragma unroll
    for (int kq = 0; kq < 4; ++kq) {
        float4 o4;
        o4.x = v[kq * 4 + 0] - ls;
        o4.y = v[kq * 4 + 1] - ls;
        o4.z = v[kq * 4 + 2] - ls;
        o4.w = v[kq * 4 + 3] - ls;
        ((float4*)OUT)[(size_t)wid * 16 + gl * 4 + kq] = o4;
    }
}

extern "C" void kernel_launch(void* const* d_in, const int* in_sizes, int n_in,
                              void* d_out, int out_size, void* d_ws, size_t ws_size,
                              hipStream_t stream) {
    const float* x = (const float*)d_in[0];
    const int* ei = (const int*)d_in[1];  // [2, NE] int32
    const float* W1 = (const float*)d_in[2];
    const float* b1 = (const float*)d_in[3];
    const float* W2 = (const float*)d_in[4];
    const float* b2 = (const float*)d_in[5];
    float* out = (float*)d_out;

    const int* src = ei;
    const int* dst = ei + NE;

    // workspace layout (all segments 16B-aligned)
    int* pcnt = (int*)d_ws;                                  // NB*NCH ints (153KB)
    uint2* rs2 = (uint2*)(pcnt + NB * NCH + 2);              // NN uint2
    float* dinv = (float*)(rs2 + NN);                        // NN
    unsigned short* Wpk1 = (unsigned short*)(dinv + NN);     // 2048*8 bf16 (32KB)
    unsigned short* Wpk2 = Wpk1 + 2048 * 8;                  // 1024*8 bf16 (16KB)
    unsigned* eord = (unsigned*)(Wpk2 + 1024 * 8);           // NB*NCH*SCAP u32 (12.3MB)
    unsigned short* esrc16 = (unsigned short*)(eord + (size_t)NB * NCH * SCAP);  // NB*ECAP u16
    unsigned* H1f8 = (unsigned*)(esrc16 + (size_t)NB * ECAP);  // (NN+1)*32 u32 (fp8, +sentinel)
    unsigned* H2f8 = H1f8 + (size_t)(NN + 1) * 32;           // (NN+1)*16 u32 (fp8, +sentinel)

    k_scat1<<<NCH + 13, 256, 0, stream>>>(src, dst, pcnt, eord, W1, W2, Wpk1, Wpk2, H1f8, H2f8);
    k_scat2g1<<<NB, 256, 0, stream>>>(pcnt, eord, esrc16, rs2, dinv, x, Wpk1, H1f8);
    k_agg1g2<<<(NN + 31) / 32, 256, 0, stream>>>(rs2, esrc16, H1f8, dinv, b1, Wpk2, H2f8);
    k_agg2_lsm<<<(((NN + 15) / 16) * 64 + 255) / 256, 256, 0, stream>>>(rs2, esrc16, H2f8,
                                                                        dinv, b2, out);
}